// Round 10
// baseline (253.083 us; speedup 1.0000x reference)
//
#include <hip/hip_runtime.h>

#define NTOK 16384
#define CCH  256
#define DH   128

typedef float f32x4  __attribute__((ext_vector_type(4)));
typedef short bf16x8 __attribute__((ext_vector_type(8)));
typedef short bf16x4 __attribute__((ext_vector_type(4)));

__device__ __forceinline__ unsigned short f2bf(float f) {
    unsigned int u = __builtin_bit_cast(unsigned int, f);
    u += 0x7fffu + ((u >> 16) & 1u);   // round-to-nearest-even
    return (unsigned short)(u >> 16);
}
__device__ __forceinline__ float bf2f(unsigned short h) {
    unsigned int u = ((unsigned int)h) << 16;
    return __builtin_bit_cast(float, u);
}
// fast round-half-up bf16 (hot loop only; inputs positive finite)
__device__ __forceinline__ unsigned short f2bf_fast(float f) {
    unsigned int u = __builtin_bit_cast(unsigned int, f);
    return (unsigned short)((u + 0x8000u) >> 16);
}
// async global->LDS DMA, 16 B/lane. LDS dest = wave-uniform base + lane*16.
__device__ __forceinline__ void load_lds16(const unsigned short* g, unsigned short* l) {
    __builtin_amdgcn_global_load_lds(
        (const __attribute__((address_space(1))) unsigned int*)g,
        (__attribute__((address_space(3))) unsigned int*)l, 16, 0, 0);
}

// ---------------------------------------------------------------------------
// Kernel 0: one-shot W fp32 -> bf16 conversion (same f2bf rounding as the
// old per-block conversion => bit-identical downstream numerics).
// Wqkv_bf: [wch][o 128][c 256] flat; Wo_bf: [c 256][o 128] flat.
// 131072 elements, 4/thread, 128 blocks.
// ---------------------------------------------------------------------------
__global__ __launch_bounds__(256) void prep_w(
    const float* __restrict__ Wq, const float* __restrict__ Wk,
    const float* __restrict__ Wv, const float* __restrict__ Wo,
    unsigned short* __restrict__ Wqkv_bf, unsigned short* __restrict__ Wo_bf)
{
    int idx4 = (blockIdx.x * 256 + threadIdx.x) * 4;
    if (idx4 < 98304) {
        int wch = idx4 >> 15;
        int off = idx4 & 32767;
        const float* W = (wch == 0) ? Wq : ((wch == 1) ? Wk : Wv);
        float4 v = *(const float4*)(W + off);
        bf16x4 pk = { (short)f2bf(v.x), (short)f2bf(v.y),
                      (short)f2bf(v.z), (short)f2bf(v.w) };
        *(bf16x4*)(Wqkv_bf + idx4) = pk;
    } else {
        int off = idx4 - 98304;
        float4 v = *(const float4*)(Wo + off);
        bf16x4 pk = { (short)f2bf(v.x), (short)f2bf(v.y),
                      (short)f2bf(v.z), (short)f2bf(v.w) };
        *(bf16x4*)(Wo_bf + off) = pk;
    }
}

// ---------------------------------------------------------------------------
// Kernel 1 (fused): q/k/v = W @ x (+bias), bf16. Q,K [N][128]; V [128][N].
// Round 16: NO W LDS staging at all. W is pre-converted bf16 (L2-resident,
// 192 KB); each MFMA A-fragment is a 16 B/lane contiguous global read (64 B
// row segments per 16-lane group). Only x needs LDS (transpose). Schedule:
// stage lX once -> ONE barrier -> 8 k-iters of {2 ds_read + 6 global bf16x8
// + 12 MFMA}, zero barriers in the loop. LDS 48 KB -> 17 KB.
// ---------------------------------------------------------------------------
__global__ __launch_bounds__(256) void qkv_fused(
    const float* __restrict__ x, const unsigned short* __restrict__ Wqkv_bf,
    const float* __restrict__ bq, const float* __restrict__ bk,
    const float* __restrict__ bv,
    unsigned short* __restrict__ Qb, unsigned short* __restrict__ Kb,
    unsigned short* __restrict__ Vb)
{
    __shared__ unsigned short lX[32 * 264];       // [n 32][c 256 + pad 8]  16.9 KB

    const int t    = threadIdx.x;
    const int wave = t >> 6, lane = t & 63, l16 = lane & 15, quad = lane >> 4;
    const int nt   = blockIdx.x;                  // 32-token tile

    // stage x tile [256 c][32 n] -> lX[n][c] (bf16, transposed)
#pragma unroll
    for (int pass = 0; pass < 8; ++pass) {
        int c  = pass * 32 + (t >> 3);
        int n4 = t & 7;
        float4 xv = *(const float4*)(x + c * NTOK + nt * 32 + n4 * 4);
        lX[(n4 * 4 + 0) * 264 + c] = f2bf(xv.x);
        lX[(n4 * 4 + 1) * 264 + c] = f2bf(xv.y);
        lX[(n4 * 4 + 2) * 264 + c] = f2bf(xv.z);
        lX[(n4 * 4 + 3) * 264 + c] = f2bf(xv.w);
    }
    __syncthreads();    // the ONLY barrier

    // wave owns o-rows [wave*32, wave*32+32): os in {0,1}; ns in {0,1}
    f32x4 acc[3][2][2];
#pragma unroll
    for (int wch = 0; wch < 3; ++wch)
#pragma unroll
        for (int os = 0; os < 2; ++os)
#pragma unroll
            for (int ns = 0; ns < 2; ++ns) acc[wch][os][ns] = (f32x4){0, 0, 0, 0};

    for (int kc8 = 0; kc8 < 8; ++kc8) {
        bf16x8 bfr[2];
#pragma unroll
        for (int ns = 0; ns < 2; ++ns)
            bfr[ns] = *(const bf16x8*)(&lX[(ns * 16 + l16) * 264 + kc8 * 32 + quad * 8]);
#pragma unroll
        for (int wch = 0; wch < 3; ++wch)
#pragma unroll
            for (int os = 0; os < 2; ++os) {
                bf16x8 afr = *(const bf16x8*)(Wqkv_bf + wch * 32768
                                              + (wave * 32 + os * 16 + l16) * CCH
                                              + kc8 * 32 + quad * 8);
                acc[wch][os][0] = __builtin_amdgcn_mfma_f32_16x16x32_bf16(afr, bfr[0], acc[wch][os][0], 0, 0, 0);
                acc[wch][os][1] = __builtin_amdgcn_mfma_f32_16x16x32_bf16(afr, bfr[1], acc[wch][os][1], 0, 0, 0);
            }
    }

    // epilogue per which: D row = o, col = n
#pragma unroll
    for (int wch = 0; wch < 3; ++wch) {
        const float* bias = (wch == 0) ? bq : ((wch == 1) ? bk : bv);
        const float oscale = (wch == 0) ? 0.0625f * 1.44269504f : 1.0f;
#pragma unroll
        for (int os = 0; os < 2; ++os)
#pragma unroll
            for (int ns = 0; ns < 2; ++ns)
#pragma unroll
                for (int r = 0; r < 4; ++r) {
                    int o = wave * 32 + os * 16 + quad * 4 + r;
                    int n = nt * 32 + ns * 16 + l16;
                    float v = (acc[wch][os][ns][r] + bias[o]) * oscale;
                    if (wch == 2)       Vb[o * NTOK + n] = f2bf(v);
                    else if (wch == 0)  Qb[n * DH + o]   = f2bf(v);
                    else                Kb[n * DH + o]   = f2bf(v);
                }
    }
}

// ---------------------------------------------------------------------------
// Kernel 2: split-K flash attention. UNCHANGED from Round 8 (proven 162 us,
// VGPR 104, no spill). 256 thr, 4 waves x 32 q-rows, single-buffered K/V,
// 48 KB LDS, KSPLIT=8 (path A) or 4 (path B).
// ---------------------------------------------------------------------------
#define LPS 64

__global__ __launch_bounds__(256, 2) void flash_attn(
    const unsigned short* __restrict__ Qb, const unsigned short* __restrict__ Kb,
    const unsigned short* __restrict__ Vb,
    unsigned short* __restrict__ P0, unsigned short* __restrict__ P123,
    float* __restrict__ lbuf, int niter)
{
    __shared__ unsigned short lK[64 * DH];       // 16384 B  [key 64][d 128] swizzled
    __shared__ unsigned short lV[DH * 64];       // 16384 B  [d 128][key 64] swizzled
    __shared__ unsigned short lP[4 * 32 * LPS];  // 16384 B  per-wave [row 32][key 64 xor-swz]

    const int t    = threadIdx.x;
    const int wave = t >> 6, lane = t & 63, l16 = lane & 15, quad = lane >> 4;
    const int qrow0 = blockIdx.x * 128 + wave * 32;
    const int split = blockIdx.y;
    const int tile0 = split * niter;
    const int xorP  = (l16 & 7) << 3;             // lP swizzle (row&7 == l16&7)

    bf16x8 qa[2][4];
#pragma unroll
    for (int h = 0; h < 2; ++h)
#pragma unroll
        for (int kc = 0; kc < 4; ++kc)
            qa[h][kc] = *(const bf16x8*)(Qb + (qrow0 + h * 16 + l16) * DH + kc * 32 + quad * 8);

    f32x4 acc[2][8];
#pragma unroll
    for (int h = 0; h < 2; ++h)
#pragma unroll
        for (int i = 0; i < 8; ++i) acc[h][i] = (f32x4){0, 0, 0, 0};
    float lpart[2] = {0.f, 0.f};   // per-lane l partial for qrow = h*16 + l16

    for (int it = 0; it < niter; ++it) {
        __syncthreads();    // previous tile's LDS reads done
        {
            const unsigned short* Kt = Kb + (size_t)(tile0 + it) * 64 * DH;
            const int vcol = (tile0 + it) * 64;
#pragma unroll
            for (int p = 0; p < 4; ++p) {
                int s = p * 256 + t;
                int key = s >> 4, c16 = s & 15;
                load_lds16(Kt + key * DH + ((c16 ^ (key & 15)) << 3),
                           &lK[(p * 256 + wave * 64) * 8]);
                int vr = s >> 3, vc = s & 7;
                load_lds16(Vb + vr * NTOK + vcol + ((vc ^ (vr & 7)) << 3),
                           &lV[(p * 256 + wave * 64) * 8]);
            }
        }
        __syncthreads();    // DMA drained (vmcnt(0) before barrier)

        // S^T = K Q^T : lane holds col=qrow, rows=keys
        f32x4 sf[2][4];
#pragma unroll
        for (int h = 0; h < 2; ++h)
#pragma unroll
            for (int ns = 0; ns < 4; ++ns) sf[h][ns] = (f32x4){0, 0, 0, 0};
        __builtin_amdgcn_s_setprio(1);
#pragma unroll
        for (int kc = 0; kc < 4; ++kc) {
#pragma unroll
            for (int ns = 0; ns < 4; ++ns) {
                bf16x8 kb = *(const bf16x8*)(&lK[(ns * 16 + l16) * DH + (((kc * 4 + quad) ^ l16) << 3)]);
                sf[0][ns] = __builtin_amdgcn_mfma_f32_16x16x32_bf16(kb, qa[0][kc], sf[0][ns], 0, 0, 0);
                sf[1][ns] = __builtin_amdgcn_mfma_f32_16x16x32_bf16(kb, qa[1][kc], sf[1][ns], 0, 0, 0);
            }
        }
        __builtin_amdgcn_s_setprio(0);

        // p = 2^s; per-lane l; P^T -> per-wave LDS as packed b64 (xor-swizzled)
        unsigned short* pb = &lP[wave * 32 * LPS];
#pragma unroll
        for (int h = 0; h < 2; ++h)
#pragma unroll
            for (int ns = 0; ns < 4; ++ns) {
                float p0 = __builtin_amdgcn_exp2f(sf[h][ns][0]);
                float p1 = __builtin_amdgcn_exp2f(sf[h][ns][1]);
                float p2 = __builtin_amdgcn_exp2f(sf[h][ns][2]);
                float p3 = __builtin_amdgcn_exp2f(sf[h][ns][3]);
                lpart[h] += (p0 + p1) + (p2 + p3);
                bf16x4 pk = { (short)f2bf_fast(p0), (short)f2bf_fast(p1),
                              (short)f2bf_fast(p2), (short)f2bf_fast(p3) };
                *(bf16x4*)(pb + (h * 16 + l16) * LPS + ((ns * 16 + quad * 4) ^ xorP)) = pk;
            }

        bf16x8 pa[2][2];
#pragma unroll
        for (int h = 0; h < 2; ++h)
#pragma unroll
            for (int half = 0; half < 2; ++half)
                pa[h][half] = *(const bf16x8*)(pb + (h * 16 + l16) * LPS + ((half * 32 + quad * 8) ^ xorP));

        __builtin_amdgcn_s_setprio(1);
#pragma unroll
        for (int ds = 0; ds < 8; ++ds) {
            bf16x8 vb0 = *(const bf16x8*)(&lV[(ds * 16 + l16) * 64 + ((quad ^ (l16 & 7)) << 3)]);
            bf16x8 vb1 = *(const bf16x8*)(&lV[(ds * 16 + l16) * 64 + (((4 + quad) ^ (l16 & 7)) << 3)]);
            acc[0][ds] = __builtin_amdgcn_mfma_f32_16x16x32_bf16(pa[0][0], vb0, acc[0][ds], 0, 0, 0);
            acc[0][ds] = __builtin_amdgcn_mfma_f32_16x16x32_bf16(pa[0][1], vb1, acc[0][ds], 0, 0, 0);
            acc[1][ds] = __builtin_amdgcn_mfma_f32_16x16x32_bf16(pa[1][0], vb0, acc[1][ds], 0, 0, 0);
            acc[1][ds] = __builtin_amdgcn_mfma_f32_16x16x32_bf16(pa[1][1], vb1, acc[1][ds], 0, 0, 0);
        }
        __builtin_amdgcn_s_setprio(0);
    }

    float lsum[2];
#pragma unroll
    for (int h = 0; h < 2; ++h) {
        float s = lpart[h];
        s += __shfl_xor(s, 16);
        s += __shfl_xor(s, 32);
        lsum[h] = s;
    }

    unsigned short* base = (split == 0) ? P0 : (P123 + (size_t)(split - 1) * NTOK * DH);
#pragma unroll
    for (int h = 0; h < 2; ++h) {
        float inv[4];
#pragma unroll
        for (int r = 0; r < 4; ++r)
            inv[r] = 1.0f / __shfl(lsum[h], quad * 4 + r, 16);
#pragma unroll
        for (int ds = 0; ds < 8; ++ds)
#pragma unroll
            for (int r = 0; r < 4; ++r) {
                int row = qrow0 + h * 16 + quad * 4 + r;
                base[row * DH + ds * 16 + l16] = f2bf(acc[h][ds][r] * inv[r]);
            }
        if (quad == 0)
            lbuf[split * NTOK + qrow0 + h * 16 + l16] = lsum[h];
    }
}

// ---------------------------------------------------------------------------
// Kernel 2b: combine NS partials -> Ob bf16 [N][128]. In-place over the
// split-0 partial; consumes scratch BEFORE out_proj writes d_out.
// ---------------------------------------------------------------------------
template <int NS>
__global__ __launch_bounds__(256) void combine(
    const unsigned short* __restrict__ P123, const float* __restrict__ lbuf,
    unsigned short* __restrict__ Ob)
{
    const int t = threadIdx.x;
    const int n  = blockIdx.x * 32 + (t >> 3);
    const int sg = t & 7;

    const unsigned short* Pp[NS];
    Pp[0] = Ob;
#pragma unroll
    for (int s = 1; s < NS; ++s) Pp[s] = P123 + (size_t)(s - 1) * NTOK * DH;

    float w[NS], den = 0.f;
#pragma unroll
    for (int s = 0; s < NS; ++s) { w[s] = lbuf[s * NTOK + n]; den += w[s]; }
    float invden = 1.0f / den;
#pragma unroll
    for (int s = 0; s < NS; ++s) w[s] *= invden;

#pragma unroll
    for (int j = 0; j < 2; ++j) {
        bf16x8 v[NS];
#pragma unroll
        for (int s = 0; s < NS; ++s)
            v[s] = *(const bf16x8*)(Pp[s] + n * DH + sg * 16 + j * 8);
        bf16x8 o;
#pragma unroll
        for (int e = 0; e < 8; ++e) {
            float a = 0.f;
#pragma unroll
            for (int s = 0; s < NS; ++s)
                a += w[s] * bf2f((unsigned short)v[s][e]);
            o[e] = (short)f2bf(a);
        }
        *(bf16x8*)(Ob + n * DH + sg * 16 + j * 8) = o;
    }
}

// ---------------------------------------------------------------------------
// Kernel 3: out = Wo @ O^T + bo + x (residual), fp32.
// Wo staged from pre-converted bf16 (one barrier, once per block).
// Epilogue round-trips acc through a padded LDS tile for float4 emit.
// grid 512: blockIdx.x&1 = c-half, blockIdx.x>>1 = 64-token tile.
// ---------------------------------------------------------------------------
__global__ __launch_bounds__(256) void out_proj(
    const unsigned short* __restrict__ Wo_bf, const float* __restrict__ bo,
    const float* __restrict__ x, const unsigned short* __restrict__ Ob,
    float* __restrict__ out)
{
    __shared__ unsigned short lW[DH * 72];   // [c 128][o 128 + pad 8]  18.4 KB
    __shared__ float lsO[DH * 68];           // [c 128][n 64 + pad 4]   34.8 KB

    const int t    = threadIdx.x;
    const int wave = t >> 6, lane = t & 63, l16 = lane & 15, quad = lane >> 4;
    const int ch = blockIdx.x & 1;
    const int n0 = (blockIdx.x >> 1) * 64;
    const int c0 = ch * 128;

#pragma unroll
    for (int i = 0; i < 8; ++i) {
        int s = i * 256 + t;
        int row = s >> 4, oct = s & 15;
        bf16x8 wv = *(const bf16x8*)(Wo_bf + (c0 + row) * DH + oct * 8);
        *(bf16x8*)(&lW[row * 72 + oct * 8]) = wv;
    }
    __syncthreads();

    f32x4 acc[8];
#pragma unroll
    for (int i = 0; i < 8; ++i) acc[i] = (f32x4){0, 0, 0, 0};

#pragma unroll
    for (int kc = 0; kc < 4; ++kc) {
        bf16x8 bfr = *(const bf16x8*)(Ob + (n0 + wave * 16 + l16) * DH + kc * 32 + quad * 8);
#pragma unroll
        for (int cs = 0; cs < 8; ++cs) {
            bf16x8 afr = *(const bf16x8*)(&lW[(cs * 16 + l16) * 72 + kc * 32 + quad * 8]);
            acc[cs] = __builtin_amdgcn_mfma_f32_16x16x32_bf16(afr, bfr, acc[cs], 0, 0, 0);
        }
    }

    // acc -> LDS tile (2-way banking via stride 68)
#pragma unroll
    for (int cs = 0; cs < 8; ++cs)
#pragma unroll
        for (int r = 0; r < 4; ++r)
            lsO[(cs * 16 + quad * 4 + r) * 68 + wave * 16 + l16] = acc[cs][r];
    __syncthreads();

    // coalesced emit: thread -> (c, 4 consecutive n); 256 B segments
#pragma unroll
    for (int it = 0; it < 8; ++it) {
        int idx = it * 256 + t;
        int c  = idx >> 4;          // 0..127
        int n4 = idx & 15;          // 0..15 -> 4-float group
        float4 v = *(const float4*)(&lsO[c * 68 + n4 * 4]);
        float4 xv = *(const float4*)(x + (size_t)(c0 + c) * NTOK + n0 + n4 * 4);
        float b = bo[c0 + c];
        float4 o = { v.x + b + xv.x, v.y + b + xv.y, v.z + b + xv.z, v.w + b + xv.w };
        *(float4*)(out + (size_t)(c0 + c) * NTOK + n0 + n4 * 4) = o;
    }
}

// ---------------------------------------------------------------------------
extern "C" void kernel_launch(void* const* d_in, const int* in_sizes, int n_in,
                              void* d_out, int out_size, void* d_ws, size_t ws_size,
                              hipStream_t stream) {
    const float* x  = (const float*)d_in[0];
    const float* Wq = (const float*)d_in[1];
    const float* bq = (const float*)d_in[2];
    const float* Wk = (const float*)d_in[3];
    const float* bk = (const float*)d_in[4];
    const float* Wv = (const float*)d_in[5];
    const float* bv = (const float*)d_in[6];
    const float* Wo = (const float*)d_in[7];
    const float* bo = (const float*)d_in[8];
    float* out = (float*)d_out;

    char* w = (char*)d_ws;
    unsigned short* Qb = (unsigned short*)(w);                  // 4 MB  [N][128] bf16
    unsigned short* Kb = (unsigned short*)(w + (4u << 20));     // 4 MB  [N][128] bf16
    unsigned short* Vb = (unsigned short*)(w + (8u << 20));     // 4 MB  [128][N] bf16
    unsigned short* Ob = (unsigned short*)(w + (12u << 20));    // 4 MB: split-0 partial, then combined O

    // Path A (KSPLIT=8) scratch map in ws:
    //   [16M..44M)   P123: 7 partials
    //   [44M..44.5M) lbuf: 8 x NTOK floats
    //   [44.5M..+256K) Wqkv_bf (192K) + Wo_bf (64K)
    const size_t lbuf_off  = (44u << 20);
    const size_t wbf_offA  = lbuf_off + 8 * NTOK * sizeof(float);
    const size_t needA     = wbf_offA + (256u << 10);

    if (ws_size >= needA) {
        unsigned short* P123    = (unsigned short*)(w + (16u << 20));
        float*          lbuf    = (float*)(w + lbuf_off);
        unsigned short* Wqkv_bf = (unsigned short*)(w + wbf_offA);
        unsigned short* Wo_bf   = Wqkv_bf + 3 * DH * CCH;

        prep_w<<<128, 256, 0, stream>>>(Wq, Wk, Wv, Wo, Wqkv_bf, Wo_bf);
        qkv_fused<<<512, 256, 0, stream>>>(x, Wqkv_bf, bq, bk, bv, Qb, Kb, Vb);
        flash_attn<<<dim3(128, 8), 256, 0, stream>>>(Qb, Kb, Vb, Ob, P123, lbuf, 32);
        combine<8><<<512, 256, 0, stream>>>(P123, lbuf, Ob);
        out_proj<<<512, 256, 0, stream>>>(Wo_bf, bo, x, Ob, out);
    } else {
        // Path B: KSPLIT=4; partials 1..3 + lbuf in d_out (consumed by combine
        // before out_proj writes d_out); W-bf right after the 16 MB in ws.
        unsigned short* P123    = (unsigned short*)d_out;
        float*          lbuf    = (float*)((char*)d_out + (12u << 20));
        unsigned short* Wqkv_bf = (unsigned short*)(w + (16u << 20));
        unsigned short* Wo_bf   = Wqkv_bf + 3 * DH * CCH;

        prep_w<<<128, 256, 0, stream>>>(Wq, Wk, Wv, Wo, Wqkv_bf, Wo_bf);
        qkv_fused<<<512, 256, 0, stream>>>(x, Wqkv_bf, bq, bk, bv, Qb, Kb, Vb);
        flash_attn<<<dim3(128, 4), 256, 0, stream>>>(Qb, Kb, Vb, Ob, P123, lbuf, 64);
        combine<4><<<512, 256, 0, stream>>>(P123, lbuf, Ob);
        out_proj<<<512, 256, 0, stream>>>(Wo_bf, bo, x, Ob, out);
    }
}

// Round 12
// 243.752 us; speedup vs baseline: 1.0383x; 1.0383x over previous
//
#include <hip/hip_runtime.h>

#define NTOK 16384
#define CCH  256
#define DH   128
#define KSPLIT 4

typedef float f32x4  __attribute__((ext_vector_type(4)));
typedef short bf16x8 __attribute__((ext_vector_type(8)));
typedef short bf16x4 __attribute__((ext_vector_type(4)));

__device__ __forceinline__ unsigned short f2bf(float f) {
    unsigned int u = __builtin_bit_cast(unsigned int, f);
    u += 0x7fffu + ((u >> 16) & 1u);   // round-to-nearest-even
    return (unsigned short)(u >> 16);
}
__device__ __forceinline__ float bf2f(unsigned short h) {
    unsigned int u = ((unsigned int)h) << 16;
    return __builtin_bit_cast(float, u);
}
// fast round-half-up bf16 (hot loop only; inputs positive finite)
__device__ __forceinline__ unsigned short f2bf_fast(float f) {
    unsigned int u = __builtin_bit_cast(unsigned int, f);
    return (unsigned short)((u + 0x8000u) >> 16);
}
// async global->LDS DMA, 16 B/lane. LDS dest = wave-uniform base + lane*16.
__device__ __forceinline__ void load_lds16(const unsigned short* g, unsigned short* l) {
    __builtin_amdgcn_global_load_lds(
        (const __attribute__((address_space(1))) unsigned int*)g,
        (__attribute__((address_space(3))) unsigned int*)l, 16, 0, 0);
}

// ---------------------------------------------------------------------------
// Kernel 0: one-shot W fp32 -> bf16 conversion (same f2bf rounding as the
// old per-block conversion => bit-identical downstream numerics).
// Wqkv_bf: [wch][o 128][c 256] flat; Wo_bf: [c 256][o 128] flat.
// ---------------------------------------------------------------------------
__global__ __launch_bounds__(256) void prep_w(
    const float* __restrict__ Wq, const float* __restrict__ Wk,
    const float* __restrict__ Wv, const float* __restrict__ Wo,
    unsigned short* __restrict__ Wqkv_bf, unsigned short* __restrict__ Wo_bf)
{
    int idx4 = (blockIdx.x * 256 + threadIdx.x) * 4;
    if (idx4 < 98304) {
        int wch = idx4 >> 15;
        int off = idx4 & 32767;
        const float* W = (wch == 0) ? Wq : ((wch == 1) ? Wk : Wv);
        float4 v = *(const float4*)(W + off);
        bf16x4 pk = { (short)f2bf(v.x), (short)f2bf(v.y),
                      (short)f2bf(v.z), (short)f2bf(v.w) };
        *(bf16x4*)(Wqkv_bf + idx4) = pk;
    } else {
        int off = idx4 - 98304;
        float4 v = *(const float4*)(Wo + off);
        bf16x4 pk = { (short)f2bf(v.x), (short)f2bf(v.y),
                      (short)f2bf(v.z), (short)f2bf(v.w) };
        *(bf16x4*)(Wo_bf + off) = pk;
    }
}

// ---------------------------------------------------------------------------
// Kernel 1 (fused): q/k/v = W @ x (+bias), bf16. Q,K [N][128]; V [128][N].
// R9 main loop (LDS-staged bf16 W -- proven best) + coalesced epilogue:
// outputs round-trip through the dead lX buffer so Q/K emit as 256 B
// contiguous rows (was per-lane 2B scatter) and V emits 64 B per 4-lane
// group (was 32 B segments).
// ---------------------------------------------------------------------------
__global__ __launch_bounds__(256) void qkv_fused(
    const float* __restrict__ x, const unsigned short* __restrict__ Wqkv_bf,
    const float* __restrict__ bq, const float* __restrict__ bk,
    const float* __restrict__ bv,
    unsigned short* __restrict__ Qb, unsigned short* __restrict__ Kb,
    unsigned short* __restrict__ Vb)
{
    __shared__ unsigned short lX[32 * 264];       // [n 32][c 256 + pad 8]  16.9 KB
    __shared__ unsigned short lW[3 * DH * 40];    // [which][o 128][c 32 + pad]  30.7 KB

    const int t    = threadIdx.x;
    const int wave = t >> 6, lane = t & 63, l16 = lane & 15, quad = lane >> 4;
    const int nt   = blockIdx.x;                  // 32-token tile

    // stage x tile [256 c][32 n] -> lX[n][c] (bf16, transposed)
#pragma unroll
    for (int pass = 0; pass < 8; ++pass) {
        int c  = pass * 32 + (t >> 3);
        int n4 = t & 7;
        float4 xv = *(const float4*)(x + c * NTOK + nt * 32 + n4 * 4);
        lX[(n4 * 4 + 0) * 264 + c] = f2bf(xv.x);
        lX[(n4 * 4 + 1) * 264 + c] = f2bf(xv.y);
        lX[(n4 * 4 + 2) * 264 + c] = f2bf(xv.z);
        lX[(n4 * 4 + 3) * 264 + c] = f2bf(xv.w);
    }

    // wave owns o-rows [wave*32, wave*32+32): os in {0,1}; ns in {0,1}
    f32x4 acc[3][2][2];
#pragma unroll
    for (int wch = 0; wch < 3; ++wch)
#pragma unroll
        for (int os = 0; os < 2; ++os)
#pragma unroll
            for (int ns = 0; ns < 2; ++ns) acc[wch][os][ns] = (f32x4){0, 0, 0, 0};

    for (int kc8 = 0; kc8 < 8; ++kc8) {
        __syncthreads();
        // stage W chunks [128 o][32 c] for q,k,v from pre-converted bf16
#pragma unroll
        for (int wch = 0; wch < 3; ++wch) {
            const unsigned short* Wb = Wqkv_bf + wch * 32768;
#pragma unroll
            for (int p = 0; p < 2; ++p) {
                int s = p * 256 + t;
                int row = s >> 2, oct = s & 3;
                bf16x8 wv = *(const bf16x8*)(Wb + row * CCH + kc8 * 32 + oct * 8);
                *(bf16x8*)(&lW[wch * DH * 40 + row * 40 + oct * 8]) = wv;
            }
        }
        __syncthreads();

        bf16x8 bfr[2];
#pragma unroll
        for (int ns = 0; ns < 2; ++ns)
            bfr[ns] = *(const bf16x8*)(&lX[(ns * 16 + l16) * 264 + kc8 * 32 + quad * 8]);
#pragma unroll
        for (int wch = 0; wch < 3; ++wch)
#pragma unroll
            for (int os = 0; os < 2; ++os) {
                bf16x8 afr = *(const bf16x8*)(&lW[wch * DH * 40 + (wave * 32 + os * 16 + l16) * 40 + quad * 8]);
                acc[wch][os][0] = __builtin_amdgcn_mfma_f32_16x16x32_bf16(afr, bfr[0], acc[wch][os][0], 0, 0, 0);
                acc[wch][os][1] = __builtin_amdgcn_mfma_f32_16x16x32_bf16(afr, bfr[1], acc[wch][os][1], 0, 0, 0);
            }
    }

    // ---- coalesced epilogue via LDS transpose (lX reused; dead after loop) --
    unsigned short* lE = lX;

    // Q then K: tile [n 32][o 128] stride 136 (rows 16B-aligned, ~2-way banks)
#pragma unroll
    for (int wch = 0; wch < 2; ++wch) {
        const float* bias = (wch == 0) ? bq : bk;
        const float oscale = (wch == 0) ? 0.0625f * 1.44269504f : 1.0f;
        __syncthreads();   // previous lE use (lX reads / prior emit) complete
#pragma unroll
        for (int os = 0; os < 2; ++os)
#pragma unroll
            for (int ns = 0; ns < 2; ++ns) {
                int o0 = wave * 32 + os * 16 + quad * 4;
                bf16x4 pk;
#pragma unroll
                for (int r = 0; r < 4; ++r)
                    pk[r] = (short)f2bf((acc[wch][os][ns][r] + bias[o0 + r]) * oscale);
                *(bf16x4*)(&lE[(ns * 16 + l16) * 136 + o0]) = pk;
            }
        __syncthreads();
        unsigned short* dst = (wch == 0) ? Qb : Kb;
#pragma unroll
        for (int it = 0; it < 2; ++it) {
            int idx = it * 256 + t;
            int n = idx >> 4, o8 = idx & 15;
            *(bf16x8*)(dst + (size_t)(nt * 32 + n) * DH + o8 * 8) =
                *(const bf16x8*)(&lE[n * 136 + o8 * 8]);
        }
    }

    // V: tile [o 128][n 32] stride 40 (rows 16B-aligned)
    __syncthreads();
#pragma unroll
    for (int os = 0; os < 2; ++os)
#pragma unroll
        for (int ns = 0; ns < 2; ++ns)
#pragma unroll
            for (int r = 0; r < 4; ++r) {
                int o = wave * 32 + os * 16 + quad * 4 + r;
                int n = ns * 16 + l16;
                lE[o * 40 + n] = f2bf(acc[2][os][ns][r] + bv[o]);
            }
    __syncthreads();
#pragma unroll
    for (int it = 0; it < 2; ++it) {
        int idx = it * 256 + t;
        int o = idx >> 2, f = idx & 3;
        *(bf16x8*)(Vb + (size_t)o * NTOK + nt * 32 + f * 8) =
            *(const bf16x8*)(&lE[o * 40 + f * 8]);
    }
}

// ---------------------------------------------------------------------------
// Kernel 2: split-K flash attention. UNCHANGED body from Round 8 (proven
// 162 us, VGPR 104, no spill). KSPLIT=4 both paths (niter=64); combine
// traffic halves vs KSPLIT=8, flash timing equivalent (R0: 160.3).
// ---------------------------------------------------------------------------
#define LPS 64

__global__ __launch_bounds__(256, 2) void flash_attn(
    const unsigned short* __restrict__ Qb, const unsigned short* __restrict__ Kb,
    const unsigned short* __restrict__ Vb,
    unsigned short* __restrict__ P0, unsigned short* __restrict__ P123,
    float* __restrict__ lbuf, int niter)
{
    __shared__ unsigned short lK[64 * DH];       // 16384 B  [key 64][d 128] swizzled
    __shared__ unsigned short lV[DH * 64];       // 16384 B  [d 128][key 64] swizzled
    __shared__ unsigned short lP[4 * 32 * LPS];  // 16384 B  per-wave [row 32][key 64 xor-swz]

    const int t    = threadIdx.x;
    const int wave = t >> 6, lane = t & 63, l16 = lane & 15, quad = lane >> 4;
    const int qrow0 = blockIdx.x * 128 + wave * 32;
    const int split = blockIdx.y;
    const int tile0 = split * niter;
    const int xorP  = (l16 & 7) << 3;             // lP swizzle (row&7 == l16&7)

    bf16x8 qa[2][4];
#pragma unroll
    for (int h = 0; h < 2; ++h)
#pragma unroll
        for (int kc = 0; kc < 4; ++kc)
            qa[h][kc] = *(const bf16x8*)(Qb + (qrow0 + h * 16 + l16) * DH + kc * 32 + quad * 8);

    f32x4 acc[2][8];
#pragma unroll
    for (int h = 0; h < 2; ++h)
#pragma unroll
        for (int i = 0; i < 8; ++i) acc[h][i] = (f32x4){0, 0, 0, 0};
    float lpart[2] = {0.f, 0.f};   // per-lane l partial for qrow = h*16 + l16

    for (int it = 0; it < niter; ++it) {
        __syncthreads();    // previous tile's LDS reads done
        {
            const unsigned short* Kt = Kb + (size_t)(tile0 + it) * 64 * DH;
            const int vcol = (tile0 + it) * 64;
#pragma unroll
            for (int p = 0; p < 4; ++p) {
                int s = p * 256 + t;
                int key = s >> 4, c16 = s & 15;
                load_lds16(Kt + key * DH + ((c16 ^ (key & 15)) << 3),
                           &lK[(p * 256 + wave * 64) * 8]);
                int vr = s >> 3, vc = s & 7;
                load_lds16(Vb + vr * NTOK + vcol + ((vc ^ (vr & 7)) << 3),
                           &lV[(p * 256 + wave * 64) * 8]);
            }
        }
        __syncthreads();    // DMA drained (vmcnt(0) before barrier)

        // S^T = K Q^T : lane holds col=qrow, rows=keys
        f32x4 sf[2][4];
#pragma unroll
        for (int h = 0; h < 2; ++h)
#pragma unroll
            for (int ns = 0; ns < 4; ++ns) sf[h][ns] = (f32x4){0, 0, 0, 0};
        __builtin_amdgcn_s_setprio(1);
#pragma unroll
        for (int kc = 0; kc < 4; ++kc) {
#pragma unroll
            for (int ns = 0; ns < 4; ++ns) {
                bf16x8 kb = *(const bf16x8*)(&lK[(ns * 16 + l16) * DH + (((kc * 4 + quad) ^ l16) << 3)]);
                sf[0][ns] = __builtin_amdgcn_mfma_f32_16x16x32_bf16(kb, qa[0][kc], sf[0][ns], 0, 0, 0);
                sf[1][ns] = __builtin_amdgcn_mfma_f32_16x16x32_bf16(kb, qa[1][kc], sf[1][ns], 0, 0, 0);
            }
        }
        __builtin_amdgcn_s_setprio(0);

        // p = 2^s; per-lane l; P^T -> per-wave LDS as packed b64 (xor-swizzled)
        unsigned short* pb = &lP[wave * 32 * LPS];
#pragma unroll
        for (int h = 0; h < 2; ++h)
#pragma unroll
            for (int ns = 0; ns < 4; ++ns) {
                float p0 = __builtin_amdgcn_exp2f(sf[h][ns][0]);
                float p1 = __builtin_amdgcn_exp2f(sf[h][ns][1]);
                float p2 = __builtin_amdgcn_exp2f(sf[h][ns][2]);
                float p3 = __builtin_amdgcn_exp2f(sf[h][ns][3]);
                lpart[h] += (p0 + p1) + (p2 + p3);
                bf16x4 pk = { (short)f2bf_fast(p0), (short)f2bf_fast(p1),
                              (short)f2bf_fast(p2), (short)f2bf_fast(p3) };
                *(bf16x4*)(pb + (h * 16 + l16) * LPS + ((ns * 16 + quad * 4) ^ xorP)) = pk;
            }

        bf16x8 pa[2][2];
#pragma unroll
        for (int h = 0; h < 2; ++h)
#pragma unroll
            for (int half = 0; half < 2; ++half)
                pa[h][half] = *(const bf16x8*)(pb + (h * 16 + l16) * LPS + ((half * 32 + quad * 8) ^ xorP));

        __builtin_amdgcn_s_setprio(1);
#pragma unroll
        for (int ds = 0; ds < 8; ++ds) {
            bf16x8 vb0 = *(const bf16x8*)(&lV[(ds * 16 + l16) * 64 + ((quad ^ (l16 & 7)) << 3)]);
            bf16x8 vb1 = *(const bf16x8*)(&lV[(ds * 16 + l16) * 64 + (((4 + quad) ^ (l16 & 7)) << 3)]);
            acc[0][ds] = __builtin_amdgcn_mfma_f32_16x16x32_bf16(pa[0][0], vb0, acc[0][ds], 0, 0, 0);
            acc[0][ds] = __builtin_amdgcn_mfma_f32_16x16x32_bf16(pa[0][1], vb1, acc[0][ds], 0, 0, 0);
            acc[1][ds] = __builtin_amdgcn_mfma_f32_16x16x32_bf16(pa[1][0], vb0, acc[1][ds], 0, 0, 0);
            acc[1][ds] = __builtin_amdgcn_mfma_f32_16x16x32_bf16(pa[1][1], vb1, acc[1][ds], 0, 0, 0);
        }
        __builtin_amdgcn_s_setprio(0);
    }

    float lsum[2];
#pragma unroll
    for (int h = 0; h < 2; ++h) {
        float s = lpart[h];
        s += __shfl_xor(s, 16);
        s += __shfl_xor(s, 32);
        lsum[h] = s;
    }

    unsigned short* base = (split == 0) ? P0 : (P123 + (size_t)(split - 1) * NTOK * DH);
#pragma unroll
    for (int h = 0; h < 2; ++h) {
        float inv[4];
#pragma unroll
        for (int r = 0; r < 4; ++r)
            inv[r] = 1.0f / __shfl(lsum[h], quad * 4 + r, 16);
#pragma unroll
        for (int ds = 0; ds < 8; ++ds)
#pragma unroll
            for (int r = 0; r < 4; ++r) {
                int row = qrow0 + h * 16 + quad * 4 + r;
                base[row * DH + ds * 16 + l16] = f2bf(acc[h][ds][r] * inv[r]);
            }
        if (quad == 0)
            lbuf[split * NTOK + qrow0 + h * 16 + l16] = lsum[h];
    }
}

// ---------------------------------------------------------------------------
// Kernel 2b: combine NS partials -> Ob bf16 [N][128]. In-place over the
// split-0 partial; consumes scratch BEFORE out_proj writes d_out.
// ---------------------------------------------------------------------------
template <int NS>
__global__ __launch_bounds__(256) void combine(
    const unsigned short* __restrict__ P123, const float* __restrict__ lbuf,
    unsigned short* __restrict__ Ob)
{
    const int t = threadIdx.x;
    const int n  = blockIdx.x * 32 + (t >> 3);
    const int sg = t & 7;

    const unsigned short* Pp[NS];
    Pp[0] = Ob;
#pragma unroll
    for (int s = 1; s < NS; ++s) Pp[s] = P123 + (size_t)(s - 1) * NTOK * DH;

    float w[NS], den = 0.f;
#pragma unroll
    for (int s = 0; s < NS; ++s) { w[s] = lbuf[s * NTOK + n]; den += w[s]; }
    float invden = 1.0f / den;
#pragma unroll
    for (int s = 0; s < NS; ++s) w[s] *= invden;

#pragma unroll
    for (int j = 0; j < 2; ++j) {
        bf16x8 v[NS];
#pragma unroll
        for (int s = 0; s < NS; ++s)
            v[s] = *(const bf16x8*)(Pp[s] + n * DH + sg * 16 + j * 8);
        bf16x8 o;
#pragma unroll
        for (int e = 0; e < 8; ++e) {
            float a = 0.f;
#pragma unroll
            for (int s = 0; s < NS; ++s)
                a += w[s] * bf2f((unsigned short)v[s][e]);
            o[e] = (short)f2bf(a);
        }
        *(bf16x8*)(Ob + n * DH + sg * 16 + j * 8) = o;
    }
}

// ---------------------------------------------------------------------------
// Kernel 3: out = Wo @ O^T + bo + x (residual), fp32.
// Wo staged from pre-converted bf16 (one barrier, once per block).
// Epilogue round-trips acc through a padded LDS tile for float4 emit.
// grid 512: blockIdx.x&1 = c-half, blockIdx.x>>1 = 64-token tile.
// ---------------------------------------------------------------------------
__global__ __launch_bounds__(256) void out_proj(
    const unsigned short* __restrict__ Wo_bf, const float* __restrict__ bo,
    const float* __restrict__ x, const unsigned short* __restrict__ Ob,
    float* __restrict__ out)
{
    __shared__ unsigned short lW[DH * 72];   // [c 128][o 128 + pad 8]  18.4 KB
    __shared__ float lsO[DH * 68];           // [c 128][n 64 + pad 4]   34.8 KB

    const int t    = threadIdx.x;
    const int wave = t >> 6, lane = t & 63, l16 = lane & 15, quad = lane >> 4;
    const int ch = blockIdx.x & 1;
    const int n0 = (blockIdx.x >> 1) * 64;
    const int c0 = ch * 128;

#pragma unroll
    for (int i = 0; i < 8; ++i) {
        int s = i * 256 + t;
        int row = s >> 4, oct = s & 15;
        bf16x8 wv = *(const bf16x8*)(Wo_bf + (c0 + row) * DH + oct * 8);
        *(bf16x8*)(&lW[row * 72 + oct * 8]) = wv;
    }
    __syncthreads();

    f32x4 acc[8];
#pragma unroll
    for (int i = 0; i < 8; ++i) acc[i] = (f32x4){0, 0, 0, 0};

#pragma unroll
    for (int kc = 0; kc < 4; ++kc) {
        bf16x8 bfr = *(const bf16x8*)(Ob + (n0 + wave * 16 + l16) * DH + kc * 32 + quad * 8);
#pragma unroll
        for (int cs = 0; cs < 8; ++cs) {
            bf16x8 afr = *(const bf16x8*)(&lW[(cs * 16 + l16) * 72 + kc * 32 + quad * 8]);
            acc[cs] = __builtin_amdgcn_mfma_f32_16x16x32_bf16(afr, bfr, acc[cs], 0, 0, 0);
        }
    }

    // acc -> LDS tile (2-way banking via stride 68)
#pragma unroll
    for (int cs = 0; cs < 8; ++cs)
#pragma unroll
        for (int r = 0; r < 4; ++r)
            lsO[(cs * 16 + quad * 4 + r) * 68 + wave * 16 + l16] = acc[cs][r];
    __syncthreads();

    // coalesced emit: thread -> (c, 4 consecutive n); 256 B segments
#pragma unroll
    for (int it = 0; it < 8; ++it) {
        int idx = it * 256 + t;
        int c  = idx >> 4;          // 0..127
        int n4 = idx & 15;          // 0..15 -> 4-float group
        float4 v = *(const float4*)(&lsO[c * 68 + n4 * 4]);
        float4 xv = *(const float4*)(x + (size_t)(c0 + c) * NTOK + n0 + n4 * 4);
        float b = bo[c0 + c];
        float4 o = { v.x + b + xv.x, v.y + b + xv.y, v.z + b + xv.z, v.w + b + xv.w };
        *(float4*)(out + (size_t)(c0 + c) * NTOK + n0 + n4 * 4) = o;
    }
}

// ---------------------------------------------------------------------------
extern "C" void kernel_launch(void* const* d_in, const int* in_sizes, int n_in,
                              void* d_out, int out_size, void* d_ws, size_t ws_size,
                              hipStream_t stream) {
    const float* x  = (const float*)d_in[0];
    const float* Wq = (const float*)d_in[1];
    const float* bq = (const float*)d_in[2];
    const float* Wk = (const float*)d_in[3];
    const float* bk = (const float*)d_in[4];
    const float* Wv = (const float*)d_in[5];
    const float* bv = (const float*)d_in[6];
    const float* Wo = (const float*)d_in[7];
    const float* bo = (const float*)d_in[8];
    float* out = (float*)d_out;

    char* w = (char*)d_ws;
    unsigned short* Qb = (unsigned short*)(w);                  // 4 MB  [N][128] bf16
    unsigned short* Kb = (unsigned short*)(w + (4u << 20));     // 4 MB  [N][128] bf16
    unsigned short* Vb = (unsigned short*)(w + (8u << 20));     // 4 MB  [128][N] bf16
    unsigned short* Ob = (unsigned short*)(w + (12u << 20));    // 4 MB: split-0 partial, then combined O

    // Path A (KSPLIT=4) scratch map in ws:
    //   [16M..28M)     P123: 3 partials
    //   [28M..28.25M)  lbuf: 4 x NTOK floats
    //   [28.25M..+256K) Wqkv_bf (192K) + Wo_bf (64K)
    const size_t lbuf_off  = (28u << 20);
    const size_t wbf_offA  = lbuf_off + KSPLIT * NTOK * sizeof(float);
    const size_t needA     = wbf_offA + (256u << 10);

    if (ws_size >= needA) {
        unsigned short* P123    = (unsigned short*)(w + (16u << 20));
        float*          lbuf    = (float*)(w + lbuf_off);
        unsigned short* Wqkv_bf = (unsigned short*)(w + wbf_offA);
        unsigned short* Wo_bf   = Wqkv_bf + 3 * DH * CCH;

        prep_w<<<128, 256, 0, stream>>>(Wq, Wk, Wv, Wo, Wqkv_bf, Wo_bf);
        qkv_fused<<<512, 256, 0, stream>>>(x, Wqkv_bf, bq, bk, bv, Qb, Kb, Vb);
        flash_attn<<<dim3(128, KSPLIT), 256, 0, stream>>>(Qb, Kb, Vb, Ob, P123, lbuf, 64);
        combine<KSPLIT><<<512, 256, 0, stream>>>(P123, lbuf, Ob);
        out_proj<<<512, 256, 0, stream>>>(Wo_bf, bo, x, Ob, out);
    } else {
        // Path B: partials 1..3 + lbuf in d_out (consumed by combine before
        // out_proj writes d_out); W-bf right after the 16 MB in ws.
        unsigned short* P123    = (unsigned short*)d_out;
        float*          lbuf    = (float*)((char*)d_out + (12u << 20));
        unsigned short* Wqkv_bf = (unsigned short*)(w + (16u << 20));
        unsigned short* Wo_bf   = Wqkv_bf + 3 * DH * CCH;

        prep_w<<<128, 256, 0, stream>>>(Wq, Wk, Wv, Wo, Wqkv_bf, Wo_bf);
        qkv_fused<<<512, 256, 0, stream>>>(x, Wqkv_bf, bq, bk, bv, Qb, Kb, Vb);
        flash_attn<<<dim3(128, KSPLIT), 256, 0, stream>>>(Qb, Kb, Vb, Ob, P123, lbuf, 64);
        combine<KSPLIT><<<512, 256, 0, stream>>>(P123, lbuf, Ob);
        out_proj<<<512, 256, 0, stream>>>(Wo_bf, bo, x, Ob, out);
    }
}

// Round 13
// 236.295 us; speedup vs baseline: 1.0710x; 1.0316x over previous
//
#include <hip/hip_runtime.h>

#define NTOK 16384
#define CCH  256
#define DH   128
#define KSPLIT 4

typedef float f32x4  __attribute__((ext_vector_type(4)));
typedef short bf16x8 __attribute__((ext_vector_type(8)));
typedef short bf16x4 __attribute__((ext_vector_type(4)));

__device__ __forceinline__ unsigned short f2bf(float f) {
    unsigned int u = __builtin_bit_cast(unsigned int, f);
    u += 0x7fffu + ((u >> 16) & 1u);   // round-to-nearest-even
    return (unsigned short)(u >> 16);
}
__device__ __forceinline__ float bf2f(unsigned short h) {
    unsigned int u = ((unsigned int)h) << 16;
    return __builtin_bit_cast(float, u);
}
// fast round-half-up bf16 (hot loop only; inputs positive finite)
__device__ __forceinline__ unsigned short f2bf_fast(float f) {
    unsigned int u = __builtin_bit_cast(unsigned int, f);
    return (unsigned short)((u + 0x8000u) >> 16);
}
// async global->LDS DMA, 16 B/lane. LDS dest = wave-uniform base + lane*16.
__device__ __forceinline__ void load_lds16(const unsigned short* g, unsigned short* l) {
    __builtin_amdgcn_global_load_lds(
        (const __attribute__((address_space(1))) unsigned int*)g,
        (__attribute__((address_space(3))) unsigned int*)l, 16, 0, 0);
}

// ---------------------------------------------------------------------------
// Kernel 0: one-shot W fp32 -> bf16 conversion (same f2bf rounding as the
// old per-block conversion => bit-identical downstream numerics).
// Wqkv_bf: [wch][o 128][c 256] flat; Wo_bf: [c 256][o 128] flat.
// ---------------------------------------------------------------------------
__global__ __launch_bounds__(256) void prep_w(
    const float* __restrict__ Wq, const float* __restrict__ Wk,
    const float* __restrict__ Wv, const float* __restrict__ Wo,
    unsigned short* __restrict__ Wqkv_bf, unsigned short* __restrict__ Wo_bf)
{
    int idx4 = (blockIdx.x * 256 + threadIdx.x) * 4;
    if (idx4 < 98304) {
        int wch = idx4 >> 15;
        int off = idx4 & 32767;
        const float* W = (wch == 0) ? Wq : ((wch == 1) ? Wk : Wv);
        float4 v = *(const float4*)(W + off);
        bf16x4 pk = { (short)f2bf(v.x), (short)f2bf(v.y),
                      (short)f2bf(v.z), (short)f2bf(v.w) };
        *(bf16x4*)(Wqkv_bf + idx4) = pk;
    } else {
        int off = idx4 - 98304;
        float4 v = *(const float4*)(Wo + off);
        bf16x4 pk = { (short)f2bf(v.x), (short)f2bf(v.y),
                      (short)f2bf(v.z), (short)f2bf(v.w) };
        *(bf16x4*)(Wo_bf + off) = pk;
    }
}

// ---------------------------------------------------------------------------
// Kernel 1 (fused): q/k/v = W @ x (+bias), bf16. Q,K [N][128]; V [128][N].
// R9 main loop (LDS-staged bf16 W) + coalesced LDS-transpose epilogue.
// ---------------------------------------------------------------------------
__global__ __launch_bounds__(256) void qkv_fused(
    const float* __restrict__ x, const unsigned short* __restrict__ Wqkv_bf,
    const float* __restrict__ bq, const float* __restrict__ bk,
    const float* __restrict__ bv,
    unsigned short* __restrict__ Qb, unsigned short* __restrict__ Kb,
    unsigned short* __restrict__ Vb)
{
    __shared__ unsigned short lX[32 * 264];       // [n 32][c 256 + pad 8]  16.9 KB
    __shared__ unsigned short lW[3 * DH * 40];    // [which][o 128][c 32 + pad]  30.7 KB

    const int t    = threadIdx.x;
    const int wave = t >> 6, lane = t & 63, l16 = lane & 15, quad = lane >> 4;
    const int nt   = blockIdx.x;                  // 32-token tile

    // stage x tile [256 c][32 n] -> lX[n][c] (bf16, transposed)
#pragma unroll
    for (int pass = 0; pass < 8; ++pass) {
        int c  = pass * 32 + (t >> 3);
        int n4 = t & 7;
        float4 xv = *(const float4*)(x + c * NTOK + nt * 32 + n4 * 4);
        lX[(n4 * 4 + 0) * 264 + c] = f2bf(xv.x);
        lX[(n4 * 4 + 1) * 264 + c] = f2bf(xv.y);
        lX[(n4 * 4 + 2) * 264 + c] = f2bf(xv.z);
        lX[(n4 * 4 + 3) * 264 + c] = f2bf(xv.w);
    }

    // wave owns o-rows [wave*32, wave*32+32): os in {0,1}; ns in {0,1}
    f32x4 acc[3][2][2];
#pragma unroll
    for (int wch = 0; wch < 3; ++wch)
#pragma unroll
        for (int os = 0; os < 2; ++os)
#pragma unroll
            for (int ns = 0; ns < 2; ++ns) acc[wch][os][ns] = (f32x4){0, 0, 0, 0};

    for (int kc8 = 0; kc8 < 8; ++kc8) {
        __syncthreads();
        // stage W chunks [128 o][32 c] for q,k,v from pre-converted bf16
#pragma unroll
        for (int wch = 0; wch < 3; ++wch) {
            const unsigned short* Wb = Wqkv_bf + wch * 32768;
#pragma unroll
            for (int p = 0; p < 2; ++p) {
                int s = p * 256 + t;
                int row = s >> 2, oct = s & 3;
                bf16x8 wv = *(const bf16x8*)(Wb + row * CCH + kc8 * 32 + oct * 8);
                *(bf16x8*)(&lW[wch * DH * 40 + row * 40 + oct * 8]) = wv;
            }
        }
        __syncthreads();

        bf16x8 bfr[2];
#pragma unroll
        for (int ns = 0; ns < 2; ++ns)
            bfr[ns] = *(const bf16x8*)(&lX[(ns * 16 + l16) * 264 + kc8 * 32 + quad * 8]);
#pragma unroll
        for (int wch = 0; wch < 3; ++wch)
#pragma unroll
            for (int os = 0; os < 2; ++os) {
                bf16x8 afr = *(const bf16x8*)(&lW[wch * DH * 40 + (wave * 32 + os * 16 + l16) * 40 + quad * 8]);
                acc[wch][os][0] = __builtin_amdgcn_mfma_f32_16x16x32_bf16(afr, bfr[0], acc[wch][os][0], 0, 0, 0);
                acc[wch][os][1] = __builtin_amdgcn_mfma_f32_16x16x32_bf16(afr, bfr[1], acc[wch][os][1], 0, 0, 0);
            }
    }

    // ---- coalesced epilogue via LDS transpose (lX reused; dead after loop) --
    unsigned short* lE = lX;

    // Q then K: tile [n 32][o 128] stride 136 (rows 16B-aligned, ~2-way banks)
#pragma unroll
    for (int wch = 0; wch < 2; ++wch) {
        const float* bias = (wch == 0) ? bq : bk;
        const float oscale = (wch == 0) ? 0.0625f * 1.44269504f : 1.0f;
        __syncthreads();   // previous lE use (lX reads / prior emit) complete
#pragma unroll
        for (int os = 0; os < 2; ++os)
#pragma unroll
            for (int ns = 0; ns < 2; ++ns) {
                int o0 = wave * 32 + os * 16 + quad * 4;
                bf16x4 pk;
#pragma unroll
                for (int r = 0; r < 4; ++r)
                    pk[r] = (short)f2bf((acc[wch][os][ns][r] + bias[o0 + r]) * oscale);
                *(bf16x4*)(&lE[(ns * 16 + l16) * 136 + o0]) = pk;
            }
        __syncthreads();
        unsigned short* dst = (wch == 0) ? Qb : Kb;
#pragma unroll
        for (int it = 0; it < 2; ++it) {
            int idx = it * 256 + t;
            int n = idx >> 4, o8 = idx & 15;
            *(bf16x8*)(dst + (size_t)(nt * 32 + n) * DH + o8 * 8) =
                *(const bf16x8*)(&lE[n * 136 + o8 * 8]);
        }
    }

    // V: tile [o 128][n 32] stride 40 (rows 16B-aligned)
    __syncthreads();
#pragma unroll
    for (int os = 0; os < 2; ++os)
#pragma unroll
        for (int ns = 0; ns < 2; ++ns)
#pragma unroll
            for (int r = 0; r < 4; ++r) {
                int o = wave * 32 + os * 16 + quad * 4 + r;
                int n = ns * 16 + l16;
                lE[o * 40 + n] = f2bf(acc[2][os][ns][r] + bv[o]);
            }
    __syncthreads();
#pragma unroll
    for (int it = 0; it < 2; ++it) {
        int idx = it * 256 + t;
        int o = idx >> 2, f = idx & 3;
        *(bf16x8*)(Vb + (size_t)o * NTOK + nt * 32 + f * 8) =
            *(const bf16x8*)(&lE[o * 40 + f * 8]);
    }
}

// ---------------------------------------------------------------------------
// Kernel 2: split-K flash attention. UNCHANGED body (proven 155 us, VGPR
// 104, no spill). KSPLIT=4, niter=64.
// ---------------------------------------------------------------------------
#define LPS 64

__global__ __launch_bounds__(256, 2) void flash_attn(
    const unsigned short* __restrict__ Qb, const unsigned short* __restrict__ Kb,
    const unsigned short* __restrict__ Vb,
    unsigned short* __restrict__ P0, unsigned short* __restrict__ P123,
    float* __restrict__ lbuf, int niter)
{
    __shared__ unsigned short lK[64 * DH];       // 16384 B  [key 64][d 128] swizzled
    __shared__ unsigned short lV[DH * 64];       // 16384 B  [d 128][key 64] swizzled
    __shared__ unsigned short lP[4 * 32 * LPS];  // 16384 B  per-wave [row 32][key 64 xor-swz]

    const int t    = threadIdx.x;
    const int wave = t >> 6, lane = t & 63, l16 = lane & 15, quad = lane >> 4;
    const int qrow0 = blockIdx.x * 128 + wave * 32;
    const int split = blockIdx.y;
    const int tile0 = split * niter;
    const int xorP  = (l16 & 7) << 3;             // lP swizzle (row&7 == l16&7)

    bf16x8 qa[2][4];
#pragma unroll
    for (int h = 0; h < 2; ++h)
#pragma unroll
        for (int kc = 0; kc < 4; ++kc)
            qa[h][kc] = *(const bf16x8*)(Qb + (qrow0 + h * 16 + l16) * DH + kc * 32 + quad * 8);

    f32x4 acc[2][8];
#pragma unroll
    for (int h = 0; h < 2; ++h)
#pragma unroll
        for (int i = 0; i < 8; ++i) acc[h][i] = (f32x4){0, 0, 0, 0};
    float lpart[2] = {0.f, 0.f};   // per-lane l partial for qrow = h*16 + l16

    for (int it = 0; it < niter; ++it) {
        __syncthreads();    // previous tile's LDS reads done
        {
            const unsigned short* Kt = Kb + (size_t)(tile0 + it) * 64 * DH;
            const int vcol = (tile0 + it) * 64;
#pragma unroll
            for (int p = 0; p < 4; ++p) {
                int s = p * 256 + t;
                int key = s >> 4, c16 = s & 15;
                load_lds16(Kt + key * DH + ((c16 ^ (key & 15)) << 3),
                           &lK[(p * 256 + wave * 64) * 8]);
                int vr = s >> 3, vc = s & 7;
                load_lds16(Vb + vr * NTOK + vcol + ((vc ^ (vr & 7)) << 3),
                           &lV[(p * 256 + wave * 64) * 8]);
            }
        }
        __syncthreads();    // DMA drained (vmcnt(0) before barrier)

        // S^T = K Q^T : lane holds col=qrow, rows=keys
        f32x4 sf[2][4];
#pragma unroll
        for (int h = 0; h < 2; ++h)
#pragma unroll
            for (int ns = 0; ns < 4; ++ns) sf[h][ns] = (f32x4){0, 0, 0, 0};
        __builtin_amdgcn_s_setprio(1);
#pragma unroll
        for (int kc = 0; kc < 4; ++kc) {
#pragma unroll
            for (int ns = 0; ns < 4; ++ns) {
                bf16x8 kb = *(const bf16x8*)(&lK[(ns * 16 + l16) * DH + (((kc * 4 + quad) ^ l16) << 3)]);
                sf[0][ns] = __builtin_amdgcn_mfma_f32_16x16x32_bf16(kb, qa[0][kc], sf[0][ns], 0, 0, 0);
                sf[1][ns] = __builtin_amdgcn_mfma_f32_16x16x32_bf16(kb, qa[1][kc], sf[1][ns], 0, 0, 0);
            }
        }
        __builtin_amdgcn_s_setprio(0);

        // p = 2^s; per-lane l; P^T -> per-wave LDS as packed b64 (xor-swizzled)
        unsigned short* pb = &lP[wave * 32 * LPS];
#pragma unroll
        for (int h = 0; h < 2; ++h)
#pragma unroll
            for (int ns = 0; ns < 4; ++ns) {
                float p0 = __builtin_amdgcn_exp2f(sf[h][ns][0]);
                float p1 = __builtin_amdgcn_exp2f(sf[h][ns][1]);
                float p2 = __builtin_amdgcn_exp2f(sf[h][ns][2]);
                float p3 = __builtin_amdgcn_exp2f(sf[h][ns][3]);
                lpart[h] += (p0 + p1) + (p2 + p3);
                bf16x4 pk = { (short)f2bf_fast(p0), (short)f2bf_fast(p1),
                              (short)f2bf_fast(p2), (short)f2bf_fast(p3) };
                *(bf16x4*)(pb + (h * 16 + l16) * LPS + ((ns * 16 + quad * 4) ^ xorP)) = pk;
            }

        bf16x8 pa[2][2];
#pragma unroll
        for (int h = 0; h < 2; ++h)
#pragma unroll
            for (int half = 0; half < 2; ++half)
                pa[h][half] = *(const bf16x8*)(pb + (h * 16 + l16) * LPS + ((half * 32 + quad * 8) ^ xorP));

        __builtin_amdgcn_s_setprio(1);
#pragma unroll
        for (int ds = 0; ds < 8; ++ds) {
            bf16x8 vb0 = *(const bf16x8*)(&lV[(ds * 16 + l16) * 64 + ((quad ^ (l16 & 7)) << 3)]);
            bf16x8 vb1 = *(const bf16x8*)(&lV[(ds * 16 + l16) * 64 + (((4 + quad) ^ (l16 & 7)) << 3)]);
            acc[0][ds] = __builtin_amdgcn_mfma_f32_16x16x32_bf16(pa[0][0], vb0, acc[0][ds], 0, 0, 0);
            acc[0][ds] = __builtin_amdgcn_mfma_f32_16x16x32_bf16(pa[0][1], vb1, acc[0][ds], 0, 0, 0);
            acc[1][ds] = __builtin_amdgcn_mfma_f32_16x16x32_bf16(pa[1][0], vb0, acc[1][ds], 0, 0, 0);
            acc[1][ds] = __builtin_amdgcn_mfma_f32_16x16x32_bf16(pa[1][1], vb1, acc[1][ds], 0, 0, 0);
        }
        __builtin_amdgcn_s_setprio(0);
    }

    float lsum[2];
#pragma unroll
    for (int h = 0; h < 2; ++h) {
        float s = lpart[h];
        s += __shfl_xor(s, 16);
        s += __shfl_xor(s, 32);
        lsum[h] = s;
    }

    unsigned short* base = (split == 0) ? P0 : (P123 + (size_t)(split - 1) * NTOK * DH);
#pragma unroll
    for (int h = 0; h < 2; ++h) {
        float inv[4];
#pragma unroll
        for (int r = 0; r < 4; ++r)
            inv[r] = 1.0f / __shfl(lsum[h], quad * 4 + r, 16);
#pragma unroll
        for (int ds = 0; ds < 8; ++ds)
#pragma unroll
            for (int r = 0; r < 4; ++r) {
                int row = qrow0 + h * 16 + quad * 4 + r;
                base[row * DH + ds * 16 + l16] = f2bf(acc[h][ds][r] * inv[r]);
            }
        if (quad == 0)
            lbuf[split * NTOK + qrow0 + h * 16 + l16] = lsum[h];
    }
}

// ---------------------------------------------------------------------------
// Kernel 2b (path B only): combine NS partials -> Ob bf16 [N][128].
// ---------------------------------------------------------------------------
template <int NS>
__global__ __launch_bounds__(256) void combine(
    const unsigned short* __restrict__ P123, const float* __restrict__ lbuf,
    unsigned short* __restrict__ Ob)
{
    const int t = threadIdx.x;
    const int n  = blockIdx.x * 32 + (t >> 3);
    const int sg = t & 7;

    const unsigned short* Pp[NS];
    Pp[0] = Ob;
#pragma unroll
    for (int s = 1; s < NS; ++s) Pp[s] = P123 + (size_t)(s - 1) * NTOK * DH;

    float w[NS], den = 0.f;
#pragma unroll
    for (int s = 0; s < NS; ++s) { w[s] = lbuf[s * NTOK + n]; den += w[s]; }
    float invden = 1.0f / den;
#pragma unroll
    for (int s = 0; s < NS; ++s) w[s] *= invden;

#pragma unroll
    for (int j = 0; j < 2; ++j) {
        bf16x8 v[NS];
#pragma unroll
        for (int s = 0; s < NS; ++s)
            v[s] = *(const bf16x8*)(Pp[s] + n * DH + sg * 16 + j * 8);
        bf16x8 o;
#pragma unroll
        for (int e = 0; e < 8; ++e) {
            float a = 0.f;
#pragma unroll
            for (int s = 0; s < NS; ++s)
                a += w[s] * bf2f((unsigned short)v[s][e]);
            o[e] = (short)f2bf(a);
        }
        *(bf16x8*)(Ob + n * DH + sg * 16 + j * 8) = o;
    }
}

// ---------------------------------------------------------------------------
// Kernel 3 (path B): out = Wo @ O^T + bo + x, reading combined Ob.
// ---------------------------------------------------------------------------
__global__ __launch_bounds__(256) void out_proj(
    const unsigned short* __restrict__ Wo_bf, const float* __restrict__ bo,
    const float* __restrict__ x, const unsigned short* __restrict__ Ob,
    float* __restrict__ out)
{
    __shared__ unsigned short lW[DH * 72];   // [c 128][o 128 + pad 8]  18.4 KB
    __shared__ float lsO[DH * 68];           // [c 128][n 64 + pad 4]   34.8 KB

    const int t    = threadIdx.x;
    const int wave = t >> 6, lane = t & 63, l16 = lane & 15, quad = lane >> 4;
    const int ch = blockIdx.x & 1;
    const int n0 = (blockIdx.x >> 1) * 64;
    const int c0 = ch * 128;

#pragma unroll
    for (int i = 0; i < 8; ++i) {
        int s = i * 256 + t;
        int row = s >> 4, oct = s & 15;
        bf16x8 wv = *(const bf16x8*)(Wo_bf + (c0 + row) * DH + oct * 8);
        *(bf16x8*)(&lW[row * 72 + oct * 8]) = wv;
    }
    __syncthreads();

    f32x4 acc[8];
#pragma unroll
    for (int i = 0; i < 8; ++i) acc[i] = (f32x4){0, 0, 0, 0};

#pragma unroll
    for (int kc = 0; kc < 4; ++kc) {
        bf16x8 bfr = *(const bf16x8*)(Ob + (n0 + wave * 16 + l16) * DH + kc * 32 + quad * 8);
#pragma unroll
        for (int cs = 0; cs < 8; ++cs) {
            bf16x8 afr = *(const bf16x8*)(&lW[(cs * 16 + l16) * 72 + kc * 32 + quad * 8]);
            acc[cs] = __builtin_amdgcn_mfma_f32_16x16x32_bf16(afr, bfr, acc[cs], 0, 0, 0);
        }
    }

#pragma unroll
    for (int cs = 0; cs < 8; ++cs)
#pragma unroll
        for (int r = 0; r < 4; ++r)
            lsO[(cs * 16 + quad * 4 + r) * 68 + wave * 16 + l16] = acc[cs][r];
    __syncthreads();

#pragma unroll
    for (int it = 0; it < 8; ++it) {
        int idx = it * 256 + t;
        int c  = idx >> 4;
        int n4 = idx & 15;
        float4 v = *(const float4*)(&lsO[c * 68 + n4 * 4]);
        float4 xv = *(const float4*)(x + (size_t)(c0 + c) * NTOK + n0 + n4 * 4);
        float b = bo[c0 + c];
        float4 o = { v.x + b + xv.x, v.y + b + xv.y, v.z + b + xv.z, v.w + b + xv.w };
        *(float4*)(out + (size_t)(c0 + c) * NTOK + n0 + n4 * 4) = o;
    }
}

// ---------------------------------------------------------------------------
// Kernel 3' (path A): out_proj with combine FUSED. The B-fragment is formed
// inline as bfr[e] = f2bf(sum_s w[s]*bf2f(P_s[n][d])) -- bit-identical to
// combine+out_proj (same weighted sum, same f2bf, same MFMA inputs), but
// skips the Ob write/read round-trip and one dispatch. Partials all in ws,
// so no race with the d_out output writes.
// ---------------------------------------------------------------------------
template <int NS>
__global__ __launch_bounds__(256) void out_proj_fused(
    const unsigned short* __restrict__ Wo_bf, const float* __restrict__ bo,
    const float* __restrict__ x,
    const unsigned short* __restrict__ P0, const unsigned short* __restrict__ P123,
    const float* __restrict__ lbuf,
    float* __restrict__ out)
{
    __shared__ unsigned short lW[DH * 72];   // [c 128][o 128 + pad 8]  18.4 KB
    __shared__ float lsO[DH * 68];           // [c 128][n 64 + pad 4]   34.8 KB

    const int t    = threadIdx.x;
    const int wave = t >> 6, lane = t & 63, l16 = lane & 15, quad = lane >> 4;
    const int ch = blockIdx.x & 1;
    const int n0 = (blockIdx.x >> 1) * 64;
    const int c0 = ch * 128;

#pragma unroll
    for (int i = 0; i < 8; ++i) {
        int s = i * 256 + t;
        int row = s >> 4, oct = s & 15;
        bf16x8 wv = *(const bf16x8*)(Wo_bf + (c0 + row) * DH + oct * 8);
        *(bf16x8*)(&lW[row * 72 + oct * 8]) = wv;
    }

    // per-thread combine weights for row n (hoisted; B-fragment row is fixed)
    const int n = n0 + wave * 16 + l16;
    const unsigned short* Pp[NS];
    Pp[0] = P0;
#pragma unroll
    for (int s = 1; s < NS; ++s) Pp[s] = P123 + (size_t)(s - 1) * NTOK * DH;
    float wgt[NS], den = 0.f;
#pragma unroll
    for (int s = 0; s < NS; ++s) { wgt[s] = lbuf[s * NTOK + n]; den += wgt[s]; }
    float invden = 1.0f / den;
#pragma unroll
    for (int s = 0; s < NS; ++s) wgt[s] *= invden;

    __syncthreads();

    f32x4 acc[8];
#pragma unroll
    for (int i = 0; i < 8; ++i) acc[i] = (f32x4){0, 0, 0, 0};

#pragma unroll
    for (int kc = 0; kc < 4; ++kc) {
        bf16x8 v[NS];
#pragma unroll
        for (int s = 0; s < NS; ++s)
            v[s] = *(const bf16x8*)(Pp[s] + (size_t)n * DH + kc * 32 + quad * 8);
        bf16x8 bfr;
#pragma unroll
        for (int e = 0; e < 8; ++e) {
            float a = 0.f;
#pragma unroll
            for (int s = 0; s < NS; ++s)
                a += wgt[s] * bf2f((unsigned short)v[s][e]);
            bfr[e] = (short)f2bf(a);
        }
#pragma unroll
        for (int cs = 0; cs < 8; ++cs) {
            bf16x8 afr = *(const bf16x8*)(&lW[(cs * 16 + l16) * 72 + kc * 32 + quad * 8]);
            acc[cs] = __builtin_amdgcn_mfma_f32_16x16x32_bf16(afr, bfr, acc[cs], 0, 0, 0);
        }
    }

    // acc -> LDS tile (2-way banking via stride 68)
#pragma unroll
    for (int cs = 0; cs < 8; ++cs)
#pragma unroll
        for (int r = 0; r < 4; ++r)
            lsO[(cs * 16 + quad * 4 + r) * 68 + wave * 16 + l16] = acc[cs][r];
    __syncthreads();

    // coalesced emit: thread -> (c, 4 consecutive n); 256 B segments
#pragma unroll
    for (int it = 0; it < 8; ++it) {
        int idx = it * 256 + t;
        int c  = idx >> 4;
        int n4 = idx & 15;
        float4 v = *(const float4*)(&lsO[c * 68 + n4 * 4]);
        float4 xv = *(const float4*)(x + (size_t)(c0 + c) * NTOK + n0 + n4 * 4);
        float b = bo[c0 + c];
        float4 o = { v.x + b + xv.x, v.y + b + xv.y, v.z + b + xv.z, v.w + b + xv.w };
        *(float4*)(out + (size_t)(c0 + c) * NTOK + n0 + n4 * 4) = o;
    }
}

// ---------------------------------------------------------------------------
extern "C" void kernel_launch(void* const* d_in, const int* in_sizes, int n_in,
                              void* d_out, int out_size, void* d_ws, size_t ws_size,
                              hipStream_t stream) {
    const float* x  = (const float*)d_in[0];
    const float* Wq = (const float*)d_in[1];
    const float* bq = (const float*)d_in[2];
    const float* Wk = (const float*)d_in[3];
    const float* bk = (const float*)d_in[4];
    const float* Wv = (const float*)d_in[5];
    const float* bv = (const float*)d_in[6];
    const float* Wo = (const float*)d_in[7];
    const float* bo = (const float*)d_in[8];
    float* out = (float*)d_out;

    char* w = (char*)d_ws;
    unsigned short* Qb = (unsigned short*)(w);                  // 4 MB  [N][128] bf16
    unsigned short* Kb = (unsigned short*)(w + (4u << 20));     // 4 MB  [N][128] bf16
    unsigned short* Vb = (unsigned short*)(w + (8u << 20));     // 4 MB  [128][N] bf16
    unsigned short* Ob = (unsigned short*)(w + (12u << 20));    // 4 MB: split-0 partial (P0)

    // Path A (KSPLIT=4) scratch map in ws:
    //   [16M..28M)     P123: 3 partials
    //   [28M..28.25M)  lbuf: 4 x NTOK floats
    //   [28.25M..+256K) Wqkv_bf (192K) + Wo_bf (64K)
    const size_t lbuf_off  = (28u << 20);
    const size_t wbf_offA  = lbuf_off + KSPLIT * NTOK * sizeof(float);
    const size_t needA     = wbf_offA + (256u << 10);

    if (ws_size >= needA) {
        unsigned short* P123    = (unsigned short*)(w + (16u << 20));
        float*          lbuf    = (float*)(w + lbuf_off);
        unsigned short* Wqkv_bf = (unsigned short*)(w + wbf_offA);
        unsigned short* Wo_bf   = Wqkv_bf + 3 * DH * CCH;

        prep_w<<<128, 256, 0, stream>>>(Wq, Wk, Wv, Wo, Wqkv_bf, Wo_bf);
        qkv_fused<<<512, 256, 0, stream>>>(x, Wqkv_bf, bq, bk, bv, Qb, Kb, Vb);
        flash_attn<<<dim3(128, KSPLIT), 256, 0, stream>>>(Qb, Kb, Vb, Ob, P123, lbuf, 64);
        out_proj_fused<KSPLIT><<<512, 256, 0, stream>>>(Wo_bf, bo, x, Ob, P123, lbuf, out);
    } else {
        // Path B: partials 1..3 + lbuf in d_out; separate combine (fusing
        // would race out-writes against partial-reads in the same buffer).
        unsigned short* P123    = (unsigned short*)d_out;
        float*          lbuf    = (float*)((char*)d_out + (12u << 20));
        unsigned short* Wqkv_bf = (unsigned short*)(w + (16u << 20));
        unsigned short* Wo_bf   = Wqkv_bf + 3 * DH * CCH;

        prep_w<<<128, 256, 0, stream>>>(Wq, Wk, Wv, Wo, Wqkv_bf, Wo_bf);
        qkv_fused<<<512, 256, 0, stream>>>(x, Wqkv_bf, bq, bk, bv, Qb, Kb, Vb);
        flash_attn<<<dim3(128, KSPLIT), 256, 0, stream>>>(Qb, Kb, Vb, Ob, P123, lbuf, 64);
        combine<KSPLIT><<<512, 256, 0, stream>>>(P123, lbuf, Ob);
        out_proj<<<512, 256, 0, stream>>>(Wo_bf, bo, x, Ob, out);
    }
}

// Round 14
// 200.523 us; speedup vs baseline: 1.2621x; 1.1784x over previous
//
#include <hip/hip_runtime.h>

#define NTOK 16384
#define CCH  256
#define DH   128
#define KSPLIT 8

typedef float f32x4  __attribute__((ext_vector_type(4)));
typedef short bf16x8 __attribute__((ext_vector_type(8)));
typedef short bf16x4 __attribute__((ext_vector_type(4)));

__device__ __forceinline__ unsigned short f2bf(float f) {
    unsigned int u = __builtin_bit_cast(unsigned int, f);
    u += 0x7fffu + ((u >> 16) & 1u);   // round-to-nearest-even
    return (unsigned short)(u >> 16);
}
__device__ __forceinline__ float bf2f(unsigned short h) {
    unsigned int u = ((unsigned int)h) << 16;
    return __builtin_bit_cast(float, u);
}
// fast round-half-up bf16 (hot loop only; inputs positive finite)
__device__ __forceinline__ unsigned short f2bf_fast(float f) {
    unsigned int u = __builtin_bit_cast(unsigned int, f);
    return (unsigned short)((u + 0x8000u) >> 16);
}
// async global->LDS DMA, 16 B/lane. LDS dest = wave-uniform base + lane*16.
__device__ __forceinline__ void load_lds16(const unsigned short* g, unsigned short* l) {
    __builtin_amdgcn_global_load_lds(
        (const __attribute__((address_space(1))) unsigned int*)g,
        (__attribute__((address_space(3))) unsigned int*)l, 16, 0, 0);
}

// ---------------------------------------------------------------------------
// Kernel 0: one-shot W fp32 -> bf16 conversion (same f2bf rounding as the
// old per-block conversion => bit-identical downstream numerics).
// Wqkv_bf: [wch][o 128][c 256] flat; Wo_bf: [c 256][o 128] flat.
// ---------------------------------------------------------------------------
__global__ __launch_bounds__(256) void prep_w(
    const float* __restrict__ Wq, const float* __restrict__ Wk,
    const float* __restrict__ Wv, const float* __restrict__ Wo,
    unsigned short* __restrict__ Wqkv_bf, unsigned short* __restrict__ Wo_bf)
{
    int idx4 = (blockIdx.x * 256 + threadIdx.x) * 4;
    if (idx4 < 98304) {
        int wch = idx4 >> 15;
        int off = idx4 & 32767;
        const float* W = (wch == 0) ? Wq : ((wch == 1) ? Wk : Wv);
        float4 v = *(const float4*)(W + off);
        bf16x4 pk = { (short)f2bf(v.x), (short)f2bf(v.y),
                      (short)f2bf(v.z), (short)f2bf(v.w) };
        *(bf16x4*)(Wqkv_bf + idx4) = pk;
    } else {
        int off = idx4 - 98304;
        float4 v = *(const float4*)(Wo + off);
        bf16x4 pk = { (short)f2bf(v.x), (short)f2bf(v.y),
                      (short)f2bf(v.z), (short)f2bf(v.w) };
        *(bf16x4*)(Wo_bf + off) = pk;
    }
}

// ---------------------------------------------------------------------------
// Kernel 1 (fused): q/k/v = W @ x (+bias), bf16. Q,K [N][128]; V [128][N].
// R9 main loop (LDS-staged bf16 W) + coalesced LDS-transpose epilogue.
// UNCHANGED from R13.
// ---------------------------------------------------------------------------
__global__ __launch_bounds__(256) void qkv_fused(
    const float* __restrict__ x, const unsigned short* __restrict__ Wqkv_bf,
    const float* __restrict__ bq, const float* __restrict__ bk,
    const float* __restrict__ bv,
    unsigned short* __restrict__ Qb, unsigned short* __restrict__ Kb,
    unsigned short* __restrict__ Vb)
{
    __shared__ unsigned short lX[32 * 264];       // [n 32][c 256 + pad 8]  16.9 KB
    __shared__ unsigned short lW[3 * DH * 40];    // [which][o 128][c 32 + pad]  30.7 KB

    const int t    = threadIdx.x;
    const int wave = t >> 6, lane = t & 63, l16 = lane & 15, quad = lane >> 4;
    const int nt   = blockIdx.x;                  // 32-token tile

    // stage x tile [256 c][32 n] -> lX[n][c] (bf16, transposed)
#pragma unroll
    for (int pass = 0; pass < 8; ++pass) {
        int c  = pass * 32 + (t >> 3);
        int n4 = t & 7;
        float4 xv = *(const float4*)(x + c * NTOK + nt * 32 + n4 * 4);
        lX[(n4 * 4 + 0) * 264 + c] = f2bf(xv.x);
        lX[(n4 * 4 + 1) * 264 + c] = f2bf(xv.y);
        lX[(n4 * 4 + 2) * 264 + c] = f2bf(xv.z);
        lX[(n4 * 4 + 3) * 264 + c] = f2bf(xv.w);
    }

    // wave owns o-rows [wave*32, wave*32+32): os in {0,1}; ns in {0,1}
    f32x4 acc[3][2][2];
#pragma unroll
    for (int wch = 0; wch < 3; ++wch)
#pragma unroll
        for (int os = 0; os < 2; ++os)
#pragma unroll
            for (int ns = 0; ns < 2; ++ns) acc[wch][os][ns] = (f32x4){0, 0, 0, 0};

    for (int kc8 = 0; kc8 < 8; ++kc8) {
        __syncthreads();
        // stage W chunks [128 o][32 c] for q,k,v from pre-converted bf16
#pragma unroll
        for (int wch = 0; wch < 3; ++wch) {
            const unsigned short* Wb = Wqkv_bf + wch * 32768;
#pragma unroll
            for (int p = 0; p < 2; ++p) {
                int s = p * 256 + t;
                int row = s >> 2, oct = s & 3;
                bf16x8 wv = *(const bf16x8*)(Wb + row * CCH + kc8 * 32 + oct * 8);
                *(bf16x8*)(&lW[wch * DH * 40 + row * 40 + oct * 8]) = wv;
            }
        }
        __syncthreads();

        bf16x8 bfr[2];
#pragma unroll
        for (int ns = 0; ns < 2; ++ns)
            bfr[ns] = *(const bf16x8*)(&lX[(ns * 16 + l16) * 264 + kc8 * 32 + quad * 8]);
#pragma unroll
        for (int wch = 0; wch < 3; ++wch)
#pragma unroll
            for (int os = 0; os < 2; ++os) {
                bf16x8 afr = *(const bf16x8*)(&lW[wch * DH * 40 + (wave * 32 + os * 16 + l16) * 40 + quad * 8]);
                acc[wch][os][0] = __builtin_amdgcn_mfma_f32_16x16x32_bf16(afr, bfr[0], acc[wch][os][0], 0, 0, 0);
                acc[wch][os][1] = __builtin_amdgcn_mfma_f32_16x16x32_bf16(afr, bfr[1], acc[wch][os][1], 0, 0, 0);
            }
    }

    // ---- coalesced epilogue via LDS transpose (lX reused; dead after loop) --
    unsigned short* lE = lX;

    // Q then K: tile [n 32][o 128] stride 136 (rows 16B-aligned, ~2-way banks)
#pragma unroll
    for (int wch = 0; wch < 2; ++wch) {
        const float* bias = (wch == 0) ? bq : bk;
        const float oscale = (wch == 0) ? 0.0625f * 1.44269504f : 1.0f;
        __syncthreads();   // previous lE use (lX reads / prior emit) complete
#pragma unroll
        for (int os = 0; os < 2; ++os)
#pragma unroll
            for (int ns = 0; ns < 2; ++ns) {
                int o0 = wave * 32 + os * 16 + quad * 4;
                bf16x4 pk;
#pragma unroll
                for (int r = 0; r < 4; ++r)
                    pk[r] = (short)f2bf((acc[wch][os][ns][r] + bias[o0 + r]) * oscale);
                *(bf16x4*)(&lE[(ns * 16 + l16) * 136 + o0]) = pk;
            }
        __syncthreads();
        unsigned short* dst = (wch == 0) ? Qb : Kb;
#pragma unroll
        for (int it = 0; it < 2; ++it) {
            int idx = it * 256 + t;
            int n = idx >> 4, o8 = idx & 15;
            *(bf16x8*)(dst + (size_t)(nt * 32 + n) * DH + o8 * 8) =
                *(const bf16x8*)(&lE[n * 136 + o8 * 8]);
        }
    }

    // V: tile [o 128][n 32] stride 40 (rows 16B-aligned)
    __syncthreads();
#pragma unroll
    for (int os = 0; os < 2; ++os)
#pragma unroll
        for (int ns = 0; ns < 2; ++ns)
#pragma unroll
            for (int r = 0; r < 4; ++r) {
                int o = wave * 32 + os * 16 + quad * 4 + r;
                int n = ns * 16 + l16;
                lE[o * 40 + n] = f2bf(acc[2][os][ns][r] + bv[o]);
            }
    __syncthreads();
#pragma unroll
    for (int it = 0; it < 2; ++it) {
        int idx = it * 256 + t;
        int o = idx >> 2, f = idx & 3;
        *(bf16x8*)(Vb + (size_t)o * NTOK + nt * 32 + f * 8) =
            *(const bf16x8*)(&lE[o * 40 + f * 8]);
    }
}

// ---------------------------------------------------------------------------
// Kernel 2: split-K flash attention. Round 14: K DIRECT FROM GLOBAL.
// The lK swizzle algebra cancels: the kb fragment is a plain contiguous
// 16 B/lane read of Kt[row][kc*32+quad*8] -- K never needed LDS. Changes:
//  - lK deleted; staging DMA is V-only (16 KB/iter, was 32).
//  - LDS 48->32 KB -> up to 4 blocks/CU (VGPR 104 supports 16 waves/CU);
//    KSPLIT=8 (grid 128x8 = 1024) so 4 blocks/CU can be populated.
//  - T14 overlap: post-DMA barrier moved AFTER QK^T+softmax (QK^T no longer
//    reads staged data), so V's DMA drains under compute. Still 2 barriers.
// Per-wave-iter DS ops drop ~28 -> ~12; LDS bank traffic halves.
// ---------------------------------------------------------------------------
#define LPS 64

__global__ __launch_bounds__(256, 2) void flash_attn(
    const unsigned short* __restrict__ Qb, const unsigned short* __restrict__ Kb,
    const unsigned short* __restrict__ Vb,
    unsigned short* __restrict__ P0, unsigned short* __restrict__ P123,
    float* __restrict__ lbuf, int niter)
{
    __shared__ unsigned short lV[DH * 64];       // 16384 B  [d 128][key 64] swizzled
    __shared__ unsigned short lP[4 * 32 * LPS];  // 16384 B  per-wave [row 32][key 64 xor-swz]

    const int t    = threadIdx.x;
    const int wave = t >> 6, lane = t & 63, l16 = lane & 15, quad = lane >> 4;
    const int qrow0 = blockIdx.x * 128 + wave * 32;
    const int split = blockIdx.y;
    const int tile0 = split * niter;
    const int xorP  = (l16 & 7) << 3;             // lP swizzle (row&7 == l16&7)

    bf16x8 qa[2][4];
#pragma unroll
    for (int h = 0; h < 2; ++h)
#pragma unroll
        for (int kc = 0; kc < 4; ++kc)
            qa[h][kc] = *(const bf16x8*)(Qb + (qrow0 + h * 16 + l16) * DH + kc * 32 + quad * 8);

    f32x4 acc[2][8];
#pragma unroll
    for (int h = 0; h < 2; ++h)
#pragma unroll
        for (int i = 0; i < 8; ++i) acc[h][i] = (f32x4){0, 0, 0, 0};
    float lpart[2] = {0.f, 0.f};   // per-lane l partial for qrow = h*16 + l16

    for (int it = 0; it < niter; ++it) {
        __syncthreads();    // previous tile's lV reads done
        {
            const int vcol = (tile0 + it) * 64;
#pragma unroll
            for (int p = 0; p < 4; ++p) {
                int s = p * 256 + t;
                int vr = s >> 3, vc = s & 7;
                load_lds16(Vb + vr * NTOK + vcol + ((vc ^ (vr & 7)) << 3),
                           &lV[(p * 256 + wave * 64) * 8]);
            }
        }
        // NO barrier here: V DMA drains under QK^T+softmax (T14 overlap).

        // S^T = K Q^T : kb DIRECT from global (swizzle cancels; 16B/lane
        // contiguous, 64B-per-row segments, L2/L3-resident)
        const unsigned short* Kt = Kb + (size_t)(tile0 + it) * 64 * DH;
        f32x4 sf[2][4];
#pragma unroll
        for (int h = 0; h < 2; ++h)
#pragma unroll
            for (int ns = 0; ns < 4; ++ns) sf[h][ns] = (f32x4){0, 0, 0, 0};
        __builtin_amdgcn_s_setprio(1);
#pragma unroll
        for (int kc = 0; kc < 4; ++kc) {
#pragma unroll
            for (int ns = 0; ns < 4; ++ns) {
                bf16x8 kb = *(const bf16x8*)(Kt + (ns * 16 + l16) * DH + kc * 32 + quad * 8);
                sf[0][ns] = __builtin_amdgcn_mfma_f32_16x16x32_bf16(kb, qa[0][kc], sf[0][ns], 0, 0, 0);
                sf[1][ns] = __builtin_amdgcn_mfma_f32_16x16x32_bf16(kb, qa[1][kc], sf[1][ns], 0, 0, 0);
            }
        }
        __builtin_amdgcn_s_setprio(0);

        // p = 2^s; per-lane l; P^T -> per-wave LDS as packed b64 (xor-swizzled)
        unsigned short* pb = &lP[wave * 32 * LPS];
#pragma unroll
        for (int h = 0; h < 2; ++h)
#pragma unroll
            for (int ns = 0; ns < 4; ++ns) {
                float p0 = __builtin_amdgcn_exp2f(sf[h][ns][0]);
                float p1 = __builtin_amdgcn_exp2f(sf[h][ns][1]);
                float p2 = __builtin_amdgcn_exp2f(sf[h][ns][2]);
                float p3 = __builtin_amdgcn_exp2f(sf[h][ns][3]);
                lpart[h] += (p0 + p1) + (p2 + p3);
                bf16x4 pk = { (short)f2bf_fast(p0), (short)f2bf_fast(p1),
                              (short)f2bf_fast(p2), (short)f2bf_fast(p3) };
                *(bf16x4*)(pb + (h * 16 + l16) * LPS + ((ns * 16 + quad * 4) ^ xorP)) = pk;
            }

        bf16x8 pa[2][2];
#pragma unroll
        for (int h = 0; h < 2; ++h)
#pragma unroll
            for (int half = 0; half < 2; ++half)
                pa[h][half] = *(const bf16x8*)(pb + (h * 16 + l16) * LPS + ((half * 32 + quad * 8) ^ xorP));

        __syncthreads();    // V DMA drained (vmcnt(0) before barrier); lV ready

        __builtin_amdgcn_s_setprio(1);
#pragma unroll
        for (int ds = 0; ds < 8; ++ds) {
            bf16x8 vb0 = *(const bf16x8*)(&lV[(ds * 16 + l16) * 64 + ((quad ^ (l16 & 7)) << 3)]);
            bf16x8 vb1 = *(const bf16x8*)(&lV[(ds * 16 + l16) * 64 + (((4 + quad) ^ (l16 & 7)) << 3)]);
            acc[0][ds] = __builtin_amdgcn_mfma_f32_16x16x32_bf16(pa[0][0], vb0, acc[0][ds], 0, 0, 0);
            acc[0][ds] = __builtin_amdgcn_mfma_f32_16x16x32_bf16(pa[0][1], vb1, acc[0][ds], 0, 0, 0);
            acc[1][ds] = __builtin_amdgcn_mfma_f32_16x16x32_bf16(pa[1][0], vb0, acc[1][ds], 0, 0, 0);
            acc[1][ds] = __builtin_amdgcn_mfma_f32_16x16x32_bf16(pa[1][1], vb1, acc[1][ds], 0, 0, 0);
        }
        __builtin_amdgcn_s_setprio(0);
    }

    float lsum[2];
#pragma unroll
    for (int h = 0; h < 2; ++h) {
        float s = lpart[h];
        s += __shfl_xor(s, 16);
        s += __shfl_xor(s, 32);
        lsum[h] = s;
    }

    unsigned short* base = (split == 0) ? P0 : (P123 + (size_t)(split - 1) * NTOK * DH);
#pragma unroll
    for (int h = 0; h < 2; ++h) {
        float inv[4];
#pragma unroll
        for (int r = 0; r < 4; ++r)
            inv[r] = 1.0f / __shfl(lsum[h], quad * 4 + r, 16);
#pragma unroll
        for (int ds = 0; ds < 8; ++ds)
#pragma unroll
            for (int r = 0; r < 4; ++r) {
                int row = qrow0 + h * 16 + quad * 4 + r;
                base[row * DH + ds * 16 + l16] = f2bf(acc[h][ds][r] * inv[r]);
            }
        if (quad == 0)
            lbuf[split * NTOK + qrow0 + h * 16 + l16] = lsum[h];
    }
}

// ---------------------------------------------------------------------------
// Kernel 2b (path B only): combine NS partials -> Ob bf16 [N][128].
// ---------------------------------------------------------------------------
template <int NS>
__global__ __launch_bounds__(256) void combine(
    const unsigned short* __restrict__ P123, const float* __restrict__ lbuf,
    unsigned short* __restrict__ Ob)
{
    const int t = threadIdx.x;
    const int n  = blockIdx.x * 32 + (t >> 3);
    const int sg = t & 7;

    const unsigned short* Pp[NS];
    Pp[0] = Ob;
#pragma unroll
    for (int s = 1; s < NS; ++s) Pp[s] = P123 + (size_t)(s - 1) * NTOK * DH;

    float w[NS], den = 0.f;
#pragma unroll
    for (int s = 0; s < NS; ++s) { w[s] = lbuf[s * NTOK + n]; den += w[s]; }
    float invden = 1.0f / den;
#pragma unroll
    for (int s = 0; s < NS; ++s) w[s] *= invden;

#pragma unroll
    for (int j = 0; j < 2; ++j) {
        bf16x8 v[NS];
#pragma unroll
        for (int s = 0; s < NS; ++s)
            v[s] = *(const bf16x8*)(Pp[s] + n * DH + sg * 16 + j * 8);
        bf16x8 o;
#pragma unroll
        for (int e = 0; e < 8; ++e) {
            float a = 0.f;
#pragma unroll
            for (int s = 0; s < NS; ++s)
                a += w[s] * bf2f((unsigned short)v[s][e]);
            o[e] = (short)f2bf(a);
        }
        *(bf16x8*)(Ob + n * DH + sg * 16 + j * 8) = o;
    }
}

// ---------------------------------------------------------------------------
// Kernel 3 (path B): out = Wo @ O^T + bo + x, reading combined Ob.
// ---------------------------------------------------------------------------
__global__ __launch_bounds__(256) void out_proj(
    const unsigned short* __restrict__ Wo_bf, const float* __restrict__ bo,
    const float* __restrict__ x, const unsigned short* __restrict__ Ob,
    float* __restrict__ out)
{
    __shared__ unsigned short lW[DH * 72];   // [c 128][o 128 + pad 8]  18.4 KB
    __shared__ float lsO[DH * 68];           // [c 128][n 64 + pad 4]   34.8 KB

    const int t    = threadIdx.x;
    const int wave = t >> 6, lane = t & 63, l16 = lane & 15, quad = lane >> 4;
    const int ch = blockIdx.x & 1;
    const int n0 = (blockIdx.x >> 1) * 64;
    const int c0 = ch * 128;

#pragma unroll
    for (int i = 0; i < 8; ++i) {
        int s = i * 256 + t;
        int row = s >> 4, oct = s & 15;
        bf16x8 wv = *(const bf16x8*)(Wo_bf + (c0 + row) * DH + oct * 8);
        *(bf16x8*)(&lW[row * 72 + oct * 8]) = wv;
    }
    __syncthreads();

    f32x4 acc[8];
#pragma unroll
    for (int i = 0; i < 8; ++i) acc[i] = (f32x4){0, 0, 0, 0};

#pragma unroll
    for (int kc = 0; kc < 4; ++kc) {
        bf16x8 bfr = *(const bf16x8*)(Ob + (n0 + wave * 16 + l16) * DH + kc * 32 + quad * 8);
#pragma unroll
        for (int cs = 0; cs < 8; ++cs) {
            bf16x8 afr = *(const bf16x8*)(&lW[(cs * 16 + l16) * 72 + kc * 32 + quad * 8]);
            acc[cs] = __builtin_amdgcn_mfma_f32_16x16x32_bf16(afr, bfr, acc[cs], 0, 0, 0);
        }
    }

#pragma unroll
    for (int cs = 0; cs < 8; ++cs)
#pragma unroll
        for (int r = 0; r < 4; ++r)
            lsO[(cs * 16 + quad * 4 + r) * 68 + wave * 16 + l16] = acc[cs][r];
    __syncthreads();

#pragma unroll
    for (int it = 0; it < 8; ++it) {
        int idx = it * 256 + t;
        int c  = idx >> 4;
        int n4 = idx & 15;
        float4 v = *(const float4*)(&lsO[c * 68 + n4 * 4]);
        float4 xv = *(const float4*)(x + (size_t)(c0 + c) * NTOK + n0 + n4 * 4);
        float b = bo[c0 + c];
        float4 o = { v.x + b + xv.x, v.y + b + xv.y, v.z + b + xv.z, v.w + b + xv.w };
        *(float4*)(out + (size_t)(c0 + c) * NTOK + n0 + n4 * 4) = o;
    }
}

// ---------------------------------------------------------------------------
// Kernel 3' (path A): out_proj with combine FUSED (NS partials inline).
// ---------------------------------------------------------------------------
template <int NS>
__global__ __launch_bounds__(256) void out_proj_fused(
    const unsigned short* __restrict__ Wo_bf, const float* __restrict__ bo,
    const float* __restrict__ x,
    const unsigned short* __restrict__ P0, const unsigned short* __restrict__ P123,
    const float* __restrict__ lbuf,
    float* __restrict__ out)
{
    __shared__ unsigned short lW[DH * 72];   // [c 128][o 128 + pad 8]  18.4 KB
    __shared__ float lsO[DH * 68];           // [c 128][n 64 + pad 4]   34.8 KB

    const int t    = threadIdx.x;
    const int wave = t >> 6, lane = t & 63, l16 = lane & 15, quad = lane >> 4;
    const int ch = blockIdx.x & 1;
    const int n0 = (blockIdx.x >> 1) * 64;
    const int c0 = ch * 128;

#pragma unroll
    for (int i = 0; i < 8; ++i) {
        int s = i * 256 + t;
        int row = s >> 4, oct = s & 15;
        bf16x8 wv = *(const bf16x8*)(Wo_bf + (c0 + row) * DH + oct * 8);
        *(bf16x8*)(&lW[row * 72 + oct * 8]) = wv;
    }

    // per-thread combine weights for row n (hoisted; B-fragment row is fixed)
    const int n = n0 + wave * 16 + l16;
    const unsigned short* Pp[NS];
    Pp[0] = P0;
#pragma unroll
    for (int s = 1; s < NS; ++s) Pp[s] = P123 + (size_t)(s - 1) * NTOK * DH;
    float wgt[NS], den = 0.f;
#pragma unroll
    for (int s = 0; s < NS; ++s) { wgt[s] = lbuf[s * NTOK + n]; den += wgt[s]; }
    float invden = 1.0f / den;
#pragma unroll
    for (int s = 0; s < NS; ++s) wgt[s] *= invden;

    __syncthreads();

    f32x4 acc[8];
#pragma unroll
    for (int i = 0; i < 8; ++i) acc[i] = (f32x4){0, 0, 0, 0};

#pragma unroll
    for (int kc = 0; kc < 4; ++kc) {
        bf16x8 v[NS];
#pragma unroll
        for (int s = 0; s < NS; ++s)
            v[s] = *(const bf16x8*)(Pp[s] + (size_t)n * DH + kc * 32 + quad * 8);
        bf16x8 bfr;
#pragma unroll
        for (int e = 0; e < 8; ++e) {
            float a = 0.f;
#pragma unroll
            for (int s = 0; s < NS; ++s)
                a += wgt[s] * bf2f((unsigned short)v[s][e]);
            bfr[e] = (short)f2bf(a);
        }
#pragma unroll
        for (int cs = 0; cs < 8; ++cs) {
            bf16x8 afr = *(const bf16x8*)(&lW[(cs * 16 + l16) * 72 + kc * 32 + quad * 8]);
            acc[cs] = __builtin_amdgcn_mfma_f32_16x16x32_bf16(afr, bfr, acc[cs], 0, 0, 0);
        }
    }

    // acc -> LDS tile (2-way banking via stride 68)
#pragma unroll
    for (int cs = 0; cs < 8; ++cs)
#pragma unroll
        for (int r = 0; r < 4; ++r)
            lsO[(cs * 16 + quad * 4 + r) * 68 + wave * 16 + l16] = acc[cs][r];
    __syncthreads();

    // coalesced emit: thread -> (c, 4 consecutive n); 256 B segments
#pragma unroll
    for (int it = 0; it < 8; ++it) {
        int idx = it * 256 + t;
        int c  = idx >> 4;
        int n4 = idx & 15;
        float4 v = *(const float4*)(&lsO[c * 68 + n4 * 4]);
        float4 xv = *(const float4*)(x + (size_t)(c0 + c) * NTOK + n0 + n4 * 4);
        float b = bo[c0 + c];
        float4 o = { v.x + b + xv.x, v.y + b + xv.y, v.z + b + xv.z, v.w + b + xv.w };
        *(float4*)(out + (size_t)(c0 + c) * NTOK + n0 + n4 * 4) = o;
    }
}

// ---------------------------------------------------------------------------
extern "C" void kernel_launch(void* const* d_in, const int* in_sizes, int n_in,
                              void* d_out, int out_size, void* d_ws, size_t ws_size,
                              hipStream_t stream) {
    const float* x  = (const float*)d_in[0];
    const float* Wq = (const float*)d_in[1];
    const float* bq = (const float*)d_in[2];
    const float* Wk = (const float*)d_in[3];
    const float* bk = (const float*)d_in[4];
    const float* Wv = (const float*)d_in[5];
    const float* bv = (const float*)d_in[6];
    const float* Wo = (const float*)d_in[7];
    const float* bo = (const float*)d_in[8];
    float* out = (float*)d_out;

    char* w = (char*)d_ws;
    unsigned short* Qb = (unsigned short*)(w);                  // 4 MB  [N][128] bf16
    unsigned short* Kb = (unsigned short*)(w + (4u << 20));     // 4 MB  [N][128] bf16
    unsigned short* Vb = (unsigned short*)(w + (8u << 20));     // 4 MB  [128][N] bf16
    unsigned short* Ob = (unsigned short*)(w + (12u << 20));    // 4 MB: split-0 partial (P0)

    // Path A (KSPLIT=8) scratch map in ws (proven available in R8/R9):
    //   [16M..44M)     P123: 7 partials
    //   [44M..44.5M)   lbuf: 8 x NTOK floats
    //   [44.5M..+256K) Wqkv_bf (192K) + Wo_bf (64K)
    const size_t lbuf_off  = (44u << 20);
    const size_t wbf_offA  = lbuf_off + KSPLIT * NTOK * sizeof(float);
    const size_t needA     = wbf_offA + (256u << 10);

    if (ws_size >= needA) {
        unsigned short* P123    = (unsigned short*)(w + (16u << 20));
        float*          lbuf    = (float*)(w + lbuf_off);
        unsigned short* Wqkv_bf = (unsigned short*)(w + wbf_offA);
        unsigned short* Wo_bf   = Wqkv_bf + 3 * DH * CCH;

        prep_w<<<128, 256, 0, stream>>>(Wq, Wk, Wv, Wo, Wqkv_bf, Wo_bf);
        qkv_fused<<<512, 256, 0, stream>>>(x, Wqkv_bf, bq, bk, bv, Qb, Kb, Vb);
        flash_attn<<<dim3(128, KSPLIT), 256, 0, stream>>>(Qb, Kb, Vb, Ob, P123, lbuf, 256 / KSPLIT / 4);
        out_proj_fused<KSPLIT><<<512, 256, 0, stream>>>(Wo_bf, bo, x, Ob, P123, lbuf, out);
    } else {
        // Path B: KSPLIT=4; partials 1..3 + lbuf in d_out; separate combine.
        unsigned short* P123    = (unsigned short*)d_out;
        float*          lbuf    = (float*)((char*)d_out + (12u << 20));
        unsigned short* Wqkv_bf = (unsigned short*)(w + (16u << 20));
        unsigned short* Wo_bf   = Wqkv_bf + 3 * DH * CCH;

        prep_w<<<128, 256, 0, stream>>>(Wq, Wk, Wv, Wo, Wqkv_bf, Wo_bf);
        qkv_fused<<<512, 256, 0, stream>>>(x, Wqkv_bf, bq, bk, bv, Qb, Kb, Vb);
        flash_attn<<<dim3(128, 4), 256, 0, stream>>>(Qb, Kb, Vb, Ob, P123, lbuf, 64);
        combine<4><<<512, 256, 0, stream>>>(P123, lbuf, Ob);
        out_proj<<<512, 256, 0, stream>>>(Wo_bf, bo, x, Ob, out);
    }
}